// Round 4
// baseline (634.646 us; speedup 1.0000x reference)
//
#include <hip/hip_runtime.h>
#include <math.h>

#define NN 50000
#define EE 1600000
#define FIN 512
#define H1N 8
#define C2N 40
#define NEG 0.2f

// ---------------- bucketed CSR build ----------------
// Buckets of 128 dst nodes: NB = ceil(50000/128) = 391.
// Packed entry: src(16b) | dst_low7(<<16) | bucket(<<23)  -- exactly 32 bits.
#define NB 391
#define CAPG 6144            // per-bucket region capacity (mean 4348, sd ~66)
#define PA_ITEMS 8192
#define NITEMS (EE + NN)
#define PA_BLOCKS ((NITEMS + PA_ITEMS - 1) / PA_ITEMS)   // 202

// passA: coarse binning with LDS staging so global writes are contiguous runs.
__global__ __launch_bounds__(256) void passA_kernel(const int* __restrict__ ei,
    int* __restrict__ bucket_cnt, unsigned int* __restrict__ bucket_glob) {
  __shared__ int hist[NB];
  __shared__ int prefix[NB];
  __shared__ int cursor[NB];
  __shared__ int gbase[NB];
  __shared__ int scA[512], scB[512];
  __shared__ unsigned int staging[PA_ITEMS];
  int t = threadIdx.x;
  int i0 = blockIdx.x * PA_ITEMS;
  int count = NITEMS - i0; if (count > PA_ITEMS) count = PA_ITEMS;

  for (int b = t; b < NB; b += 256) hist[b] = 0;
  __syncthreads();
  // phase 1: local histogram over coarse buckets
  for (int j = t; j < count; j += 256) {
    int e = i0 + j;
    int dst = (e < EE) ? ei[EE + e] : (e - EE);
    atomicAdd(&hist[dst >> 7], 1);
  }
  __syncthreads();
  // phase 2: inclusive scan (Hillis-Steele ping-pong over 512)
  scA[t]       = (t < NB) ? hist[t] : 0;
  scA[t + 256] = (t + 256 < NB) ? hist[t + 256] : 0;
  __syncthreads();
  {
    int* pa = scA; int* pb = scB;
    for (int off = 1; off < 512; off <<= 1) {
      pb[t]       = pa[t]       + (t >= off ? pa[t - off] : 0);
      pb[t + 256] = pa[t + 256] + (t + 256 >= off ? pa[t + 256 - off] : 0);
      __syncthreads();
      int* tmp = pa; pa = pb; pb = tmp;
    }
    for (int b = t; b < NB; b += 256) {
      int ex = pa[b] - hist[b];          // exclusive prefix within block
      prefix[b] = ex;
      cursor[b] = ex;
      if (hist[b] > 0) gbase[b] = atomicAdd(&bucket_cnt[b], hist[b]);
    }
  }
  __syncthreads();
  // phase 3: group items by bucket in LDS staging
  for (int j = t; j < count; j += 256) {
    int e = i0 + j;
    int src, dst;
    if (e < EE) { src = ei[e]; dst = ei[EE + e]; }
    else        { src = e - EE; dst = src; }
    int b = dst >> 7;
    unsigned int v = (unsigned int)src | ((unsigned int)(dst & 127) << 16)
                   | ((unsigned int)b << 23);
    int lp = atomicAdd(&cursor[b], 1);
    staging[lp] = v;
  }
  __syncthreads();
  // phase 4: write runs out contiguously per bucket
  for (int j = t; j < count; j += 256) {
    unsigned int v = staging[j];
    int b = (int)(v >> 23);
    int gpos = b * CAPG + gbase[b] + (j - prefix[b]);
    bucket_glob[gpos] = v;
  }
}

// exclusive scan over 391 bucket counts -> bucket_base; also row_ptr[NN].
__global__ __launch_bounds__(512) void scan_buckets(const int* __restrict__ bucket_cnt,
    int* __restrict__ bucket_base, int* __restrict__ row_ptr_last) {
  __shared__ int scA[512], scB[512];
  int t = threadIdx.x;
  int v = (t < NB) ? bucket_cnt[t] : 0;
  scA[t] = v;
  __syncthreads();
  int* pa = scA; int* pb = scB;
  for (int off = 1; off < 512; off <<= 1) {
    pb[t] = pa[t] + (t >= off ? pa[t - off] : 0);
    __syncthreads();
    int* tmp = pa; pa = pb; pb = tmp;
  }
  if (t < NB) bucket_base[t] = pa[t] - v;
  if (t == NB - 1) *row_ptr_last = pa[t];
}

// passB: per bucket, counting-sort 128 local dsts in LDS, emit row_ptr + coalesced col.
#define CAPB 6144
__global__ __launch_bounds__(256) void passB_kernel(const unsigned int* __restrict__ bucket_glob,
    const int* __restrict__ bucket_cnt, const int* __restrict__ bucket_base,
    int* __restrict__ row_ptr, int* __restrict__ col) {
  __shared__ int hist[128], pre[128], cur[128];
  __shared__ int scA[128], scB[128];
  __shared__ int sorted[CAPB];
  int b = blockIdx.x, t = threadIdx.x;
  int cnt = bucket_cnt[b];
  int base = bucket_base[b];
  const unsigned int* in = bucket_glob + (size_t)b * CAPG;
  if (t < 128) hist[t] = 0;
  __syncthreads();
  for (int j = t; j < cnt; j += 256) {
    int dl = (int)((in[j] >> 16) & 127u);
    atomicAdd(&hist[dl], 1);
  }
  __syncthreads();
  if (t < 128) scA[t] = hist[t];
  __syncthreads();
  {
    int* pa = scA; int* pb = scB;
    for (int off = 1; off < 128; off <<= 1) {
      if (t < 128) pb[t] = pa[t] + (t >= off ? pa[t - off] : 0);
      __syncthreads();
      int* tmp = pa; pa = pb; pb = tmp;
    }
    if (t < 128) {
      int ex = pa[t] - hist[t];
      pre[t] = ex;
      cur[t] = ex;
      int d = b * 128 + t;
      if (d < NN) row_ptr[d] = base + ex;
    }
  }
  __syncthreads();
  for (int j = t; j < cnt; j += 256) {
    unsigned int v = in[j];
    int dl = (int)((v >> 16) & 127u);
    int lp = atomicAdd(&cur[dl], 1);
    sorted[lp] = (int)(v & 0xFFFFu);
  }
  __syncthreads();
  for (int j = t; j < cnt; j += 256) col[base + j] = sorted[j];
}

// ---------------- GEMM1: h1[N,64] = x[N,512] @ W1[512,64] ----------------
// Wave-independent, barrier-free, LDS-free. Each wave: 8 rows x 64 cols
// (lane = col). x rows read via same-address broadcast float4 loads (one L1
// transaction per wave), W via coalesced dword loads (L1/L2-resident 128 KB).
// Grid 1563 blocks x 4 waves -> ~24 waves/CU; zero barriers.

__global__ __launch_bounds__(256) void gemm1_kernel(const float* __restrict__ x,
    const float* __restrict__ W, float* __restrict__ h1) {
  int wave = threadIdx.x >> 6;
  int lane = threadIdx.x & 63;
  int row0 = blockIdx.x * 32 + wave * 8;
  if (row0 >= NN) return;
  const float* xr[8];
#pragma unroll
  for (int r = 0; r < 8; ++r) {
    int rr = row0 + r; if (rr > NN - 1) rr = NN - 1;   // clamp loads; store guarded
    xr[r] = x + (size_t)rr * FIN;
  }
  float acc[8] = {0.f, 0.f, 0.f, 0.f, 0.f, 0.f, 0.f, 0.f};
#pragma unroll 4
  for (int k0 = 0; k0 < FIN; k0 += 8) {
    float wv[8];
#pragma unroll
    for (int j = 0; j < 8; ++j) wv[j] = W[(size_t)(k0 + j) * 64 + lane];
#pragma unroll
    for (int r = 0; r < 8; ++r) {
      float4 a0 = *(const float4*)(xr[r] + k0);
      float4 a1 = *(const float4*)(xr[r] + k0 + 4);
      acc[r] = fmaf(a0.x, wv[0], acc[r]);
      acc[r] = fmaf(a0.y, wv[1], acc[r]);
      acc[r] = fmaf(a0.z, wv[2], acc[r]);
      acc[r] = fmaf(a0.w, wv[3], acc[r]);
      acc[r] = fmaf(a1.x, wv[4], acc[r]);
      acc[r] = fmaf(a1.y, wv[5], acc[r]);
      acc[r] = fmaf(a1.z, wv[6], acc[r]);
      acc[r] = fmaf(a1.w, wv[7], acc[r]);
    }
  }
#pragma unroll
  for (int r = 0; r < 8; ++r) {
    int rr = row0 + r;
    if (rr < NN) h1[(size_t)rr * 64 + lane] = acc[r];
  }
}

// ---------------- layer-1 attention scalars ----------------

__global__ void att1_kernel(const float* __restrict__ h1, const float* __restrict__ att_src,
    const float* __restrict__ att_dst, float* __restrict__ asrc, float* __restrict__ adst) {
  int i = blockIdx.x * blockDim.x + threadIdx.x;  // i = n*8 + h
  if (i >= NN * H1N) return;
  int h = i & 7;
  const float4* row = (const float4*)(h1 + (size_t)i * 8);
  float4 v0 = row[0], v1 = row[1];
  const float4* as = (const float4*)(att_src + h * 8);
  const float4* ad = (const float4*)(att_dst + h * 8);
  float4 s0 = as[0], s1 = as[1], d0 = ad[0], d1 = ad[1];
  float s = v0.x * s0.x + v0.y * s0.y + v0.z * s0.z + v0.w * s0.w
          + v1.x * s1.x + v1.y * s1.y + v1.z * s1.z + v1.w * s1.w;
  float d = v0.x * d0.x + v0.y * d0.y + v0.z * d0.z + v0.w * d0.w
          + v1.x * d1.x + v1.y * d1.y + v1.z * d1.z + v1.w * d1.w;
  asrc[i] = s;
  adst[i] = d;
}

// ---------------- layer-1 edge softmax + aggregate (wave per dst, unroll 8) ----------------

__global__ __launch_bounds__(256) void l1_edge_kernel(const int* __restrict__ row_ptr,
    const int* __restrict__ col, const float* __restrict__ h1,
    const float* __restrict__ asrc, const float* __restrict__ adst,
    const float* __restrict__ b1, float* __restrict__ hrelu) {
  int d = (blockIdx.x * blockDim.x + threadIdx.x) >> 6;
  int lane = threadIdx.x & 63;
  if (d >= NN) return;
  int h = lane >> 3;
  int start = row_ptr[d], end = row_ptr[d + 1];
  float adst_h = adst[d * 8 + h];
  float acc = 0.f, den = 0.f;
  int e = start;
  int nb = start + ((end - start) & ~7);
  for (; e < nb; e += 8) {
    int s[8];
#pragma unroll
    for (int j = 0; j < 8; ++j) s[j] = col[e + j];
    float av[8];
#pragma unroll
    for (int j = 0; j < 8; ++j) av[j] = asrc[s[j] * 8 + h];
    float hv[8];
#pragma unroll
    for (int j = 0; j < 8; ++j) hv[j] = h1[(size_t)s[j] * 64 + lane];
#pragma unroll
    for (int j = 0; j < 8; ++j) {
      float a = av[j] + adst_h;
      float logit = a > 0.f ? a : NEG * a;
      float ex = __expf(logit);
      den += ex;
      acc = fmaf(ex, hv[j], acc);
    }
  }
  for (; e < end; ++e) {
    int s = col[e];
    float a = asrc[s * 8 + h] + adst_h;
    float logit = a > 0.f ? a : NEG * a;
    float ex = __expf(logit);
    den += ex;
    acc = fmaf(ex, h1[(size_t)s * 64 + lane], acc);
  }
  hrelu[(size_t)d * 64 + lane] = fmaxf(acc / den + b1[lane], 0.f);
}

// ---------------- GEMM2 ----------------

__global__ __launch_bounds__(256) void gemm2_kernel(const float* __restrict__ hrelu,
    const float* __restrict__ W2, float* __restrict__ g) {
  __shared__ float w2s[64 * C2N];
  for (int i = threadIdx.x; i < 64 * C2N; i += 256) w2s[i] = W2[i];
  __syncthreads();
  int idx = blockIdx.x * 256 + threadIdx.x;
  if (idx >= NN * C2N) return;
  int n = idx / C2N;
  int c = idx - n * C2N;
  const float* hr = hrelu + (size_t)n * 64;
  float acc = 0.f;
#pragma unroll
  for (int k = 0; k < 64; ++k) acc = fmaf(hr[k], w2s[k * C2N + c], acc);
  g[idx] = acc;
}

// ---------------- layer-2 attention scalars ----------------

__global__ __launch_bounds__(256) void att2_kernel(const float* __restrict__ g,
    const float* __restrict__ att_src, const float* __restrict__ att_dst,
    float* __restrict__ asrc2, float* __restrict__ adst2) {
  int wv = (blockIdx.x * blockDim.x + threadIdx.x) >> 6;
  int lane = threadIdx.x & 63;
  if (wv >= NN) return;
  float as = 0.f, ad = 0.f;
  if (lane < C2N) {
    float v = g[(size_t)wv * C2N + lane];
    as = v * att_src[lane];
    ad = v * att_dst[lane];
  }
#pragma unroll
  for (int off = 32; off >= 1; off >>= 1) {
    as += __shfl_xor(as, off);
    ad += __shfl_xor(ad, off);
  }
  if (lane == 0) { asrc2[wv] = as; adst2[wv] = ad; }
}

// ---------------- layer-2 edge softmax + aggregate + log_softmax ----------------

__global__ __launch_bounds__(256) void l2_edge_kernel(const int* __restrict__ row_ptr,
    const int* __restrict__ col, const float* __restrict__ g,
    const float* __restrict__ asrc2, const float* __restrict__ adst2,
    const float* __restrict__ b2, float* __restrict__ out) {
  int d = (blockIdx.x * blockDim.x + threadIdx.x) >> 6;
  int lane = threadIdx.x & 63;
  if (d >= NN) return;
  int start = row_ptr[d], end = row_ptr[d + 1];
  float adst_d = adst2[d];
  bool act = lane < C2N;
  float acc = 0.f, den = 0.f;
  int e = start;
  int nb = start + ((end - start) & ~7);
  for (; e < nb; e += 8) {
    int s[8];
#pragma unroll
    for (int j = 0; j < 8; ++j) s[j] = col[e + j];
    float av[8];
#pragma unroll
    for (int j = 0; j < 8; ++j) av[j] = asrc2[s[j]];
    float gv[8];
#pragma unroll
    for (int j = 0; j < 8; ++j) gv[j] = act ? g[(size_t)s[j] * C2N + lane] : 0.f;
#pragma unroll
    for (int j = 0; j < 8; ++j) {
      float a = av[j] + adst_d;
      float logit = a > 0.f ? a : NEG * a;
      float ex = __expf(logit);
      den += ex;
      acc = fmaf(ex, gv[j], acc);
    }
  }
  for (; e < end; ++e) {
    int s = col[e];
    float a = asrc2[s] + adst_d;
    float logit = a > 0.f ? a : NEG * a;
    float ex = __expf(logit);
    den += ex;
    float gv = act ? g[(size_t)s * C2N + lane] : 0.f;
    acc = fmaf(ex, gv, acc);
  }
  float o = acc / den + (act ? b2[lane] : 0.f);
  float v = act ? o : -INFINITY;
#pragma unroll
  for (int off = 32; off >= 1; off >>= 1) v = fmaxf(v, __shfl_xor(v, off));
  float es = act ? __expf(o - v) : 0.f;
#pragma unroll
  for (int off = 32; off >= 1; off >>= 1) es += __shfl_xor(es, off);
  float ls = logf(es);
  if (act) out[(size_t)d * C2N + lane] = o - v - ls;
}

// ---------------- launch ----------------

extern "C" void kernel_launch(void* const* d_in, const int* in_sizes, int n_in,
                              void* d_out, int out_size, void* d_ws, size_t ws_size,
                              hipStream_t stream) {
  const float* x        = (const float*)d_in[0];
  const int*   ei       = (const int*)d_in[1];
  const float* W1       = (const float*)d_in[2];
  const float* att_src1 = (const float*)d_in[3];
  const float* att_dst1 = (const float*)d_in[4];
  const float* b1       = (const float*)d_in[5];
  const float* W2       = (const float*)d_in[6];
  const float* att_src2 = (const float*)d_in[7];
  const float* att_dst2 = (const float*)d_in[8];
  const float* b2       = (const float*)d_in[9];
  float* out = (float*)d_out;

  char* ws = (char*)d_ws;
  size_t off = 0;
  auto alloc = [&](size_t n_elem) {
    void* p = ws + off;
    off = (off + n_elem * 4 + 255) & ~(size_t)255;
    return p;
  };
  float* h1    = (float*)alloc((size_t)NN * 64);
  float* hrelu = (float*)alloc((size_t)NN * 64);   // also aliased as bucket_glob (9.6MB < 12.8MB)
  float* g     = (float*)alloc((size_t)NN * C2N);
  float* asrc1 = (float*)alloc((size_t)NN * 8);
  float* adst1 = (float*)alloc((size_t)NN * 8);
  float* asrc2 = (float*)alloc(NN);
  float* adst2 = (float*)alloc(NN);
  int* row_ptr = (int*)alloc(NN + 1);
  int* colv    = (int*)alloc(EE + NN);
  int* bucket_cnt  = (int*)alloc(NB);
  int* bucket_base = (int*)alloc(NB);
  unsigned int* bucket_glob = (unsigned int*)hrelu;  // consumed by passB before hrelu written

  hipMemsetAsync(bucket_cnt, 0, NB * 4, stream);
  passA_kernel<<<PA_BLOCKS, 256, 0, stream>>>(ei, bucket_cnt, bucket_glob);
  scan_buckets<<<1, 512, 0, stream>>>(bucket_cnt, bucket_base, row_ptr + NN);
  passB_kernel<<<NB, 256, 0, stream>>>(bucket_glob, bucket_cnt, bucket_base, row_ptr, colv);

  gemm1_kernel<<<(NN + 31) / 32, 256, 0, stream>>>(x, W1, h1);
  att1_kernel<<<(NN * 8 + 255) / 256, 256, 0, stream>>>(h1, att_src1, att_dst1, asrc1, adst1);
  l1_edge_kernel<<<(NN * 64 + 255) / 256, 256, 0, stream>>>(row_ptr, colv, h1, asrc1, adst1, b1, hrelu);

  gemm2_kernel<<<(NN * C2N + 255) / 256, 256, 0, stream>>>(hrelu, W2, g);
  att2_kernel<<<(NN * 64 + 255) / 256, 256, 0, stream>>>(g, att_src2, att_dst2, asrc2, adst2);
  l2_edge_kernel<<<(NN * 64 + 255) / 256, 256, 0, stream>>>(row_ptr, colv, g, asrc2, adst2, b2, out);
}

// Round 5
// 413.710 us; speedup vs baseline: 1.5340x; 1.5340x over previous
//
#include <hip/hip_runtime.h>
#include <math.h>

#define NN 50000
#define EE 1600000
#define FIN 512
#define H1N 8
#define C2N 40
#define NEG 0.2f

// ---------------- bucketed CSR build ----------------
#define NB 391
#define CAPG 6144
#define PA_ITEMS 8192
#define NITEMS (EE + NN)
#define PA_BLOCKS ((NITEMS + PA_ITEMS - 1) / PA_ITEMS)   // 202

__global__ __launch_bounds__(256) void passA_kernel(const int* __restrict__ ei,
    int* __restrict__ bucket_cnt, unsigned int* __restrict__ bucket_glob) {
  __shared__ int hist[NB];
  __shared__ int prefix[NB];
  __shared__ int cursor[NB];
  __shared__ int gbase[NB];
  __shared__ int scA[512], scB[512];
  __shared__ unsigned int staging[PA_ITEMS];
  int t = threadIdx.x;
  int i0 = blockIdx.x * PA_ITEMS;
  int count = NITEMS - i0; if (count > PA_ITEMS) count = PA_ITEMS;

  for (int b = t; b < NB; b += 256) hist[b] = 0;
  __syncthreads();
  for (int j = t; j < count; j += 256) {
    int e = i0 + j;
    int dst = (e < EE) ? ei[EE + e] : (e - EE);
    atomicAdd(&hist[dst >> 7], 1);
  }
  __syncthreads();
  scA[t]       = (t < NB) ? hist[t] : 0;
  scA[t + 256] = (t + 256 < NB) ? hist[t + 256] : 0;
  __syncthreads();
  {
    int* pa = scA; int* pb = scB;
    for (int off = 1; off < 512; off <<= 1) {
      pb[t]       = pa[t]       + (t >= off ? pa[t - off] : 0);
      pb[t + 256] = pa[t + 256] + (t + 256 >= off ? pa[t + 256 - off] : 0);
      __syncthreads();
      int* tmp = pa; pa = pb; pb = tmp;
    }
    for (int b = t; b < NB; b += 256) {
      int ex = pa[b] - hist[b];
      prefix[b] = ex;
      cursor[b] = ex;
      if (hist[b] > 0) gbase[b] = atomicAdd(&bucket_cnt[b], hist[b]);
    }
  }
  __syncthreads();
  for (int j = t; j < count; j += 256) {
    int e = i0 + j;
    int src, dst;
    if (e < EE) { src = ei[e]; dst = ei[EE + e]; }
    else        { src = e - EE; dst = src; }
    int b = dst >> 7;
    unsigned int v = (unsigned int)src | ((unsigned int)(dst & 127) << 16)
                   | ((unsigned int)b << 23);
    int lp = atomicAdd(&cursor[b], 1);
    staging[lp] = v;
  }
  __syncthreads();
  for (int j = t; j < count; j += 256) {
    unsigned int v = staging[j];
    int b = (int)(v >> 23);
    int gpos = b * CAPG + gbase[b] + (j - prefix[b]);
    bucket_glob[gpos] = v;
  }
}

__global__ __launch_bounds__(512) void scan_buckets(const int* __restrict__ bucket_cnt,
    int* __restrict__ bucket_base, int* __restrict__ row_ptr_last) {
  __shared__ int scA[512], scB[512];
  int t = threadIdx.x;
  int v = (t < NB) ? bucket_cnt[t] : 0;
  scA[t] = v;
  __syncthreads();
  int* pa = scA; int* pb = scB;
  for (int off = 1; off < 512; off <<= 1) {
    pb[t] = pa[t] + (t >= off ? pa[t - off] : 0);
    __syncthreads();
    int* tmp = pa; pa = pb; pb = tmp;
  }
  if (t < NB) bucket_base[t] = pa[t] - v;
  if (t == NB - 1) *row_ptr_last = pa[t];
}

#define CAPB 6144
__global__ __launch_bounds__(256) void passB_kernel(const unsigned int* __restrict__ bucket_glob,
    const int* __restrict__ bucket_cnt, const int* __restrict__ bucket_base,
    int* __restrict__ row_ptr, int* __restrict__ col) {
  __shared__ int hist[128], pre[128], cur[128];
  __shared__ int scA[128], scB[128];
  __shared__ int sorted[CAPB];
  int b = blockIdx.x, t = threadIdx.x;
  int cnt = bucket_cnt[b];
  int base = bucket_base[b];
  const unsigned int* in = bucket_glob + (size_t)b * CAPG;
  if (t < 128) hist[t] = 0;
  __syncthreads();
  for (int j = t; j < cnt; j += 256) {
    int dl = (int)((in[j] >> 16) & 127u);
    atomicAdd(&hist[dl], 1);
  }
  __syncthreads();
  if (t < 128) scA[t] = hist[t];
  __syncthreads();
  {
    int* pa = scA; int* pb = scB;
    for (int off = 1; off < 128; off <<= 1) {
      if (t < 128) pb[t] = pa[t] + (t >= off ? pa[t - off] : 0);
      __syncthreads();
      int* tmp = pa; pa = pb; pb = tmp;
    }
    if (t < 128) {
      int ex = pa[t] - hist[t];
      pre[t] = ex;
      cur[t] = ex;
      int d = b * 128 + t;
      if (d < NN) row_ptr[d] = base + ex;
    }
  }
  __syncthreads();
  for (int j = t; j < cnt; j += 256) {
    unsigned int v = in[j];
    int dl = (int)((v >> 16) & 127u);
    int lp = atomicAdd(&cur[dl], 1);
    sorted[lp] = (int)(v & 0xFFFFu);
  }
  __syncthreads();
  for (int j = t; j < cnt; j += 256) col[base + j] = sorted[j];
}

// ---------------- GEMM1 via bf16 MFMA ----------------
// h1[N,64] = x[N,512] @ W1[512,64].  Prep: W1T bf16 [64][512].
// Block = 256 thr, 64 rows. Per 128-k chunk: stage x f32->bf16 into LDS
// (stride 136 shorts -> 2-way banks, free), then 16x16x32 MFMA; wave owns
// 16 rows x 64 cols (4 accumulators). B-frags read from global W1T
// (64 KB, L1/L2-resident; quads of one row fetch 64 B contiguous).

typedef __attribute__((ext_vector_type(8))) short bf16x8;
typedef __attribute__((ext_vector_type(4))) float f32x4;

__device__ inline short f2bf(float f) {
  unsigned int u = __float_as_uint(f);
  u += 0x7FFFu + ((u >> 16) & 1u);     // round-to-nearest-even
  return (short)(u >> 16);
}

__global__ void w1t_kernel(const float* __restrict__ W, short* __restrict__ WT) {
  int i = blockIdx.x * 256 + threadIdx.x;   // i = n*512 + k
  if (i >= 64 * 512) return;
  int n = i >> 9, k = i & 511;
  WT[i] = f2bf(W[k * 64 + n]);
}

#define XS_STRIDE 136
__global__ __launch_bounds__(256) void gemm1_kernel(const float* __restrict__ x,
    const short* __restrict__ WT, float* __restrict__ h1) {
  __shared__ short xs[64 * XS_STRIDE];
  int t = threadIdx.x;
  int wave = t >> 6, lane = t & 63;
  int quad = lane >> 4, m = lane & 15;
  int row0 = blockIdx.x * 64;
  f32x4 acc[4] = {{0.f,0.f,0.f,0.f},{0.f,0.f,0.f,0.f},{0.f,0.f,0.f,0.f},{0.f,0.f,0.f,0.f}};
  for (int kc = 0; kc < 4; ++kc) {
    int k0 = kc * 128;
    __syncthreads();   // xs reads from previous chunk complete
#pragma unroll
    for (int jj = 0; jj < 8; ++jj) {
      int idx = jj * 256 + t;          // 0..2047 float4s of the 64x128 tile
      int row = idx >> 5, kq = idx & 31;
      int rr = row0 + row; if (rr >= NN) rr = NN - 1;
      float4 v = *(const float4*)(x + (size_t)rr * FIN + k0 + kq * 4);
      short4 s;
      s.x = f2bf(v.x); s.y = f2bf(v.y); s.z = f2bf(v.z); s.w = f2bf(v.w);
      *(short4*)&xs[row * XS_STRIDE + kq * 4] = s;
    }
    __syncthreads();
#pragma unroll
    for (int ks = 0; ks < 4; ++ks) {
      bf16x8 a = *(bf16x8*)&xs[(wave * 16 + m) * XS_STRIDE + ks * 32 + quad * 8];
#pragma unroll
      for (int tl = 0; tl < 4; ++tl) {
        bf16x8 b = *(const bf16x8*)(WT + (size_t)(tl * 16 + m) * 512 + k0 + ks * 32 + quad * 8);
        acc[tl] = __builtin_amdgcn_mfma_f32_16x16x32_bf16(a, b, acc[tl], 0, 0, 0);
      }
    }
  }
  int rbase = row0 + wave * 16 + quad * 4;
#pragma unroll
  for (int tl = 0; tl < 4; ++tl) {
#pragma unroll
    for (int r = 0; r < 4; ++r) {
      int rr = rbase + r;
      if (rr < NN) h1[(size_t)rr * 64 + tl * 16 + m] = acc[tl][r];
    }
  }
}

// ---------------- layer-1 attention scalars ----------------

__global__ void att1_kernel(const float* __restrict__ h1, const float* __restrict__ att_src,
    const float* __restrict__ att_dst, float* __restrict__ asrc, float* __restrict__ adst) {
  int i = blockIdx.x * blockDim.x + threadIdx.x;  // i = n*8 + h
  if (i >= NN * H1N) return;
  int h = i & 7;
  const float4* row = (const float4*)(h1 + (size_t)i * 8);
  float4 v0 = row[0], v1 = row[1];
  const float4* as = (const float4*)(att_src + h * 8);
  const float4* ad = (const float4*)(att_dst + h * 8);
  float4 s0 = as[0], s1 = as[1], d0 = ad[0], d1 = ad[1];
  float s = v0.x * s0.x + v0.y * s0.y + v0.z * s0.z + v0.w * s0.w
          + v1.x * s1.x + v1.y * s1.y + v1.z * s1.z + v1.w * s1.w;
  float d = v0.x * d0.x + v0.y * d0.y + v0.z * d0.z + v0.w * d0.w
          + v1.x * d1.x + v1.y * d1.y + v1.z * d1.z + v1.w * d1.w;
  asrc[i] = s;
  adst[i] = d;
}

// ---------------- layer-1 edge softmax + aggregate (wave per dst, unroll 8) ----------------

__global__ __launch_bounds__(256) void l1_edge_kernel(const int* __restrict__ row_ptr,
    const int* __restrict__ col, const float* __restrict__ h1,
    const float* __restrict__ asrc, const float* __restrict__ adst,
    const float* __restrict__ b1, float* __restrict__ hrelu) {
  int d = (blockIdx.x * blockDim.x + threadIdx.x) >> 6;
  int lane = threadIdx.x & 63;
  if (d >= NN) return;
  int h = lane >> 3;
  int start = row_ptr[d], end = row_ptr[d + 1];
  float adst_h = adst[d * 8 + h];
  float acc = 0.f, den = 0.f;
  int e = start;
  int nb = start + ((end - start) & ~7);
  for (; e < nb; e += 8) {
    int s[8];
#pragma unroll
    for (int j = 0; j < 8; ++j) s[j] = col[e + j];
    float av[8];
#pragma unroll
    for (int j = 0; j < 8; ++j) av[j] = asrc[s[j] * 8 + h];
    float hv[8];
#pragma unroll
    for (int j = 0; j < 8; ++j) hv[j] = h1[(size_t)s[j] * 64 + lane];
#pragma unroll
    for (int j = 0; j < 8; ++j) {
      float a = av[j] + adst_h;
      float logit = a > 0.f ? a : NEG * a;
      float ex = __expf(logit);
      den += ex;
      acc = fmaf(ex, hv[j], acc);
    }
  }
  for (; e < end; ++e) {
    int s = col[e];
    float a = asrc[s * 8 + h] + adst_h;
    float logit = a > 0.f ? a : NEG * a;
    float ex = __expf(logit);
    den += ex;
    acc = fmaf(ex, h1[(size_t)s * 64 + lane], acc);
  }
  hrelu[(size_t)d * 64 + lane] = fmaxf(acc / den + b1[lane], 0.f);
}

// ---------------- GEMM2 ----------------

__global__ __launch_bounds__(256) void gemm2_kernel(const float* __restrict__ hrelu,
    const float* __restrict__ W2, float* __restrict__ g) {
  __shared__ float w2s[64 * C2N];
  for (int i = threadIdx.x; i < 64 * C2N; i += 256) w2s[i] = W2[i];
  __syncthreads();
  int idx = blockIdx.x * 256 + threadIdx.x;
  if (idx >= NN * C2N) return;
  int n = idx / C2N;
  int c = idx - n * C2N;
  const float* hr = hrelu + (size_t)n * 64;
  float acc = 0.f;
#pragma unroll
  for (int k = 0; k < 64; ++k) acc = fmaf(hr[k], w2s[k * C2N + c], acc);
  g[idx] = acc;
}

// ---------------- layer-2 attention scalars ----------------

__global__ __launch_bounds__(256) void att2_kernel(const float* __restrict__ g,
    const float* __restrict__ att_src, const float* __restrict__ att_dst,
    float* __restrict__ asrc2, float* __restrict__ adst2) {
  int wv = (blockIdx.x * blockDim.x + threadIdx.x) >> 6;
  int lane = threadIdx.x & 63;
  if (wv >= NN) return;
  float as = 0.f, ad = 0.f;
  if (lane < C2N) {
    float v = g[(size_t)wv * C2N + lane];
    as = v * att_src[lane];
    ad = v * att_dst[lane];
  }
#pragma unroll
  for (int off = 32; off >= 1; off >>= 1) {
    as += __shfl_xor(as, off);
    ad += __shfl_xor(ad, off);
  }
  if (lane == 0) { asrc2[wv] = as; adst2[wv] = ad; }
}

// ---------------- layer-2 edge softmax + aggregate + log_softmax ----------------

__global__ __launch_bounds__(256) void l2_edge_kernel(const int* __restrict__ row_ptr,
    const int* __restrict__ col, const float* __restrict__ g,
    const float* __restrict__ asrc2, const float* __restrict__ adst2,
    const float* __restrict__ b2, float* __restrict__ out) {
  int d = (blockIdx.x * blockDim.x + threadIdx.x) >> 6;
  int lane = threadIdx.x & 63;
  if (d >= NN) return;
  int start = row_ptr[d], end = row_ptr[d + 1];
  float adst_d = adst2[d];
  bool act = lane < C2N;
  float acc = 0.f, den = 0.f;
  int e = start;
  int nb = start + ((end - start) & ~7);
  for (; e < nb; e += 8) {
    int s[8];
#pragma unroll
    for (int j = 0; j < 8; ++j) s[j] = col[e + j];
    float av[8];
#pragma unroll
    for (int j = 0; j < 8; ++j) av[j] = asrc2[s[j]];
    float gv[8];
#pragma unroll
    for (int j = 0; j < 8; ++j) gv[j] = act ? g[(size_t)s[j] * C2N + lane] : 0.f;
#pragma unroll
    for (int j = 0; j < 8; ++j) {
      float a = av[j] + adst_d;
      float logit = a > 0.f ? a : NEG * a;
      float ex = __expf(logit);
      den += ex;
      acc = fmaf(ex, gv[j], acc);
    }
  }
  for (; e < end; ++e) {
    int s = col[e];
    float a = asrc2[s] + adst_d;
    float logit = a > 0.f ? a : NEG * a;
    float ex = __expf(logit);
    den += ex;
    float gv = act ? g[(size_t)s * C2N + lane] : 0.f;
    acc = fmaf(ex, gv, acc);
  }
  float o = acc / den + (act ? b2[lane] : 0.f);
  float v = act ? o : -INFINITY;
#pragma unroll
  for (int off = 32; off >= 1; off >>= 1) v = fmaxf(v, __shfl_xor(v, off));
  float es = act ? __expf(o - v) : 0.f;
#pragma unroll
  for (int off = 32; off >= 1; off >>= 1) es += __shfl_xor(es, off);
  float ls = logf(es);
  if (act) out[(size_t)d * C2N + lane] = o - v - ls;
}

// ---------------- launch ----------------

extern "C" void kernel_launch(void* const* d_in, const int* in_sizes, int n_in,
                              void* d_out, int out_size, void* d_ws, size_t ws_size,
                              hipStream_t stream) {
  const float* x        = (const float*)d_in[0];
  const int*   ei       = (const int*)d_in[1];
  const float* W1       = (const float*)d_in[2];
  const float* att_src1 = (const float*)d_in[3];
  const float* att_dst1 = (const float*)d_in[4];
  const float* b1       = (const float*)d_in[5];
  const float* W2       = (const float*)d_in[6];
  const float* att_src2 = (const float*)d_in[7];
  const float* att_dst2 = (const float*)d_in[8];
  const float* b2       = (const float*)d_in[9];
  float* out = (float*)d_out;

  char* ws = (char*)d_ws;
  size_t off = 0;
  auto alloc = [&](size_t n_elem) {
    void* p = ws + off;
    off = (off + n_elem * 4 + 255) & ~(size_t)255;
    return p;
  };
  float* h1    = (float*)alloc((size_t)NN * 64);
  float* hrelu = (float*)alloc((size_t)NN * 64);   // also aliased as bucket_glob
  float* g     = (float*)alloc((size_t)NN * C2N);
  float* asrc1 = (float*)alloc((size_t)NN * 8);
  float* adst1 = (float*)alloc((size_t)NN * 8);
  float* asrc2 = (float*)alloc(NN);
  float* adst2 = (float*)alloc(NN);
  int* row_ptr = (int*)alloc(NN + 1);
  int* colv    = (int*)alloc(EE + NN);
  int* bucket_cnt  = (int*)alloc(NB);
  int* bucket_base = (int*)alloc(NB);
  short* w1t   = (short*)alloc(64 * 512 / 2);      // 64x512 bf16
  unsigned int* bucket_glob = (unsigned int*)hrelu; // consumed by passB before hrelu written

  hipMemsetAsync(bucket_cnt, 0, NB * 4, stream);
  passA_kernel<<<PA_BLOCKS, 256, 0, stream>>>(ei, bucket_cnt, bucket_glob);
  scan_buckets<<<1, 512, 0, stream>>>(bucket_cnt, bucket_base, row_ptr + NN);
  passB_kernel<<<NB, 256, 0, stream>>>(bucket_glob, bucket_cnt, bucket_base, row_ptr, colv);

  w1t_kernel<<<(64 * 512 + 255) / 256, 256, 0, stream>>>(W1, w1t);
  gemm1_kernel<<<(NN + 63) / 64, 256, 0, stream>>>(x, w1t, h1);
  att1_kernel<<<(NN * 8 + 255) / 256, 256, 0, stream>>>(h1, att_src1, att_dst1, asrc1, adst1);
  l1_edge_kernel<<<(NN * 64 + 255) / 256, 256, 0, stream>>>(row_ptr, colv, h1, asrc1, adst1, b1, hrelu);

  gemm2_kernel<<<(NN * C2N + 255) / 256, 256, 0, stream>>>(hrelu, W2, g);
  att2_kernel<<<(NN * 64 + 255) / 256, 256, 0, stream>>>(g, att_src2, att_dst2, asrc2, adst2);
  l2_edge_kernel<<<(NN * 64 + 255) / 256, 256, 0, stream>>>(row_ptr, colv, g, asrc2, adst2, b2, out);
}

// Round 6
// 367.803 us; speedup vs baseline: 1.7255x; 1.1248x over previous
//
#include <hip/hip_runtime.h>
#include <math.h>

#define NN 50000
#define EE 1600000
#define FIN 512
#define H1N 8
#define C2N 40
#define NEG 0.2f

// ---------------- bucketed CSR build ----------------
#define NB 391
#define CAPG 6144
#define PA_ITEMS 8192
#define NITEMS (EE + NN)
#define PA_BLOCKS ((NITEMS + PA_ITEMS - 1) / PA_ITEMS)   // 202

__global__ __launch_bounds__(256) void passA_kernel(const int* __restrict__ ei,
    int* __restrict__ bucket_cnt, unsigned int* __restrict__ bucket_glob) {
  __shared__ int hist[NB];
  __shared__ int prefix[NB];
  __shared__ int cursor[NB];
  __shared__ int gbase[NB];
  __shared__ int scA[512], scB[512];
  __shared__ unsigned int staging[PA_ITEMS];
  int t = threadIdx.x;
  int i0 = blockIdx.x * PA_ITEMS;
  int count = NITEMS - i0; if (count > PA_ITEMS) count = PA_ITEMS;

  for (int b = t; b < NB; b += 256) hist[b] = 0;
  __syncthreads();
  for (int j = t; j < count; j += 256) {
    int e = i0 + j;
    int dst = (e < EE) ? ei[EE + e] : (e - EE);
    atomicAdd(&hist[dst >> 7], 1);
  }
  __syncthreads();
  scA[t]       = (t < NB) ? hist[t] : 0;
  scA[t + 256] = (t + 256 < NB) ? hist[t + 256] : 0;
  __syncthreads();
  {
    int* pa = scA; int* pb = scB;
    for (int off = 1; off < 512; off <<= 1) {
      pb[t]       = pa[t]       + (t >= off ? pa[t - off] : 0);
      pb[t + 256] = pa[t + 256] + (t + 256 >= off ? pa[t + 256 - off] : 0);
      __syncthreads();
      int* tmp = pa; pa = pb; pb = tmp;
    }
    for (int b = t; b < NB; b += 256) {
      int ex = pa[b] - hist[b];
      prefix[b] = ex;
      cursor[b] = ex;
      if (hist[b] > 0) gbase[b] = atomicAdd(&bucket_cnt[b], hist[b]);
    }
  }
  __syncthreads();
  for (int j = t; j < count; j += 256) {
    int e = i0 + j;
    int src, dst;
    if (e < EE) { src = ei[e]; dst = ei[EE + e]; }
    else        { src = e - EE; dst = src; }
    int b = dst >> 7;
    unsigned int v = (unsigned int)src | ((unsigned int)(dst & 127) << 16)
                   | ((unsigned int)b << 23);
    int lp = atomicAdd(&cursor[b], 1);
    staging[lp] = v;
  }
  __syncthreads();
  for (int j = t; j < count; j += 256) {
    unsigned int v = staging[j];
    int b = (int)(v >> 23);
    int gpos = b * CAPG + gbase[b] + (j - prefix[b]);
    bucket_glob[gpos] = v;
  }
}

__global__ __launch_bounds__(512) void scan_buckets(const int* __restrict__ bucket_cnt,
    int* __restrict__ bucket_base, int* __restrict__ row_ptr_last) {
  __shared__ int scA[512], scB[512];
  int t = threadIdx.x;
  int v = (t < NB) ? bucket_cnt[t] : 0;
  scA[t] = v;
  __syncthreads();
  int* pa = scA; int* pb = scB;
  for (int off = 1; off < 512; off <<= 1) {
    pb[t] = pa[t] + (t >= off ? pa[t - off] : 0);
    __syncthreads();
    int* tmp = pa; pa = pb; pb = tmp;
  }
  if (t < NB) bucket_base[t] = pa[t] - v;
  if (t == NB - 1) *row_ptr_last = pa[t];
}

#define CAPB 6144
__global__ __launch_bounds__(256) void passB_kernel(const unsigned int* __restrict__ bucket_glob,
    const int* __restrict__ bucket_cnt, const int* __restrict__ bucket_base,
    int* __restrict__ row_ptr, int* __restrict__ col) {
  __shared__ int hist[128], pre[128], cur[128];
  __shared__ int scA[128], scB[128];
  __shared__ int sorted[CAPB];
  int b = blockIdx.x, t = threadIdx.x;
  int cnt = bucket_cnt[b];
  int base = bucket_base[b];
  const unsigned int* in = bucket_glob + (size_t)b * CAPG;
  if (t < 128) hist[t] = 0;
  __syncthreads();
  for (int j = t; j < cnt; j += 256) {
    int dl = (int)((in[j] >> 16) & 127u);
    atomicAdd(&hist[dl], 1);
  }
  __syncthreads();
  if (t < 128) scA[t] = hist[t];
  __syncthreads();
  {
    int* pa = scA; int* pb = scB;
    for (int off = 1; off < 128; off <<= 1) {
      if (t < 128) pb[t] = pa[t] + (t >= off ? pa[t - off] : 0);
      __syncthreads();
      int* tmp = pa; pa = pb; pb = tmp;
    }
    if (t < 128) {
      int ex = pa[t] - hist[t];
      pre[t] = ex;
      cur[t] = ex;
      int d = b * 128 + t;
      if (d < NN) row_ptr[d] = base + ex;
    }
  }
  __syncthreads();
  for (int j = t; j < cnt; j += 256) {
    unsigned int v = in[j];
    int dl = (int)((v >> 16) & 127u);
    int lp = atomicAdd(&cur[dl], 1);
    sorted[lp] = (int)(v & 0xFFFFu);
  }
  __syncthreads();
  for (int j = t; j < cnt; j += 256) col[base + j] = sorted[j];
}

// ---------------- bf16 helpers ----------------

typedef __attribute__((ext_vector_type(8))) short bf16x8;
typedef __attribute__((ext_vector_type(4))) float f32x4;

__device__ inline short f2bf(float f) {
  unsigned int u = __float_as_uint(f);
  u += 0x7FFFu + ((u >> 16) & 1u);     // round-to-nearest-even
  return (short)(u >> 16);
}
__device__ inline unsigned int pack2bf(float lo, float hi) {
  return (unsigned int)(unsigned short)f2bf(lo) | ((unsigned int)(unsigned short)f2bf(hi) << 16);
}
__device__ inline float bflo(unsigned int v) { return __uint_as_float(v << 16); }
__device__ inline float bfhi(unsigned int v) { return __uint_as_float(v & 0xFFFF0000u); }

// ---------------- GEMM1 via bf16 MFMA; h1 stored packed bf16 [N][32 dwords] ----------------

__global__ void w1t_kernel(const float* __restrict__ W, short* __restrict__ WT) {
  int i = blockIdx.x * 256 + threadIdx.x;   // i = n*512 + k
  if (i >= 64 * 512) return;
  int n = i >> 9, k = i & 511;
  WT[i] = f2bf(W[k * 64 + n]);
}

#define XS_STRIDE 136
__global__ __launch_bounds__(256) void gemm1_kernel(const float* __restrict__ x,
    const short* __restrict__ WT, unsigned short* __restrict__ h1b) {
  __shared__ short xs[64 * XS_STRIDE];
  int t = threadIdx.x;
  int wave = t >> 6, lane = t & 63;
  int quad = lane >> 4, m = lane & 15;
  int row0 = blockIdx.x * 64;
  f32x4 acc[4] = {{0.f,0.f,0.f,0.f},{0.f,0.f,0.f,0.f},{0.f,0.f,0.f,0.f},{0.f,0.f,0.f,0.f}};
  for (int kc = 0; kc < 4; ++kc) {
    int k0 = kc * 128;
    __syncthreads();
#pragma unroll
    for (int jj = 0; jj < 8; ++jj) {
      int idx = jj * 256 + t;
      int row = idx >> 5, kq = idx & 31;
      int rr = row0 + row; if (rr >= NN) rr = NN - 1;
      float4 v = *(const float4*)(x + (size_t)rr * FIN + k0 + kq * 4);
      short4 s;
      s.x = f2bf(v.x); s.y = f2bf(v.y); s.z = f2bf(v.z); s.w = f2bf(v.w);
      *(short4*)&xs[row * XS_STRIDE + kq * 4] = s;
    }
    __syncthreads();
#pragma unroll
    for (int ks = 0; ks < 4; ++ks) {
      bf16x8 a = *(bf16x8*)&xs[(wave * 16 + m) * XS_STRIDE + ks * 32 + quad * 8];
#pragma unroll
      for (int tl = 0; tl < 4; ++tl) {
        bf16x8 b = *(const bf16x8*)(WT + (size_t)(tl * 16 + m) * 512 + k0 + ks * 32 + quad * 8);
        acc[tl] = __builtin_amdgcn_mfma_f32_16x16x32_bf16(a, b, acc[tl], 0, 0, 0);
      }
    }
  }
  int rbase = row0 + wave * 16 + quad * 4;
#pragma unroll
  for (int tl = 0; tl < 4; ++tl) {
#pragma unroll
    for (int r = 0; r < 4; ++r) {
      int rr = rbase + r;
      if (rr < NN) h1b[(size_t)rr * 64 + tl * 16 + m] = (unsigned short)f2bf(acc[tl][r]);
    }
  }
}

// ---------------- layer-1 attention scalars (h1 packed bf16) ----------------

__global__ void att1_kernel(const unsigned int* __restrict__ h1b, const float* __restrict__ att_src,
    const float* __restrict__ att_dst, float* __restrict__ asrc, float* __restrict__ adst) {
  int i = blockIdx.x * blockDim.x + threadIdx.x;  // i = n*8 + h
  if (i >= NN * H1N) return;
  int h = i & 7;
  uint4 v = *(const uint4*)(h1b + (size_t)i * 4);  // i*4 == n*32 + h*4 dwords
  float f[8] = {bflo(v.x), bfhi(v.x), bflo(v.y), bfhi(v.y),
                bflo(v.z), bfhi(v.z), bflo(v.w), bfhi(v.w)};
  const float* as = att_src + h * 8;
  const float* ad = att_dst + h * 8;
  float s = 0.f, d = 0.f;
#pragma unroll
  for (int c = 0; c < 8; ++c) { s = fmaf(f[c], as[c], s); d = fmaf(f[c], ad[c], d); }
  asrc[i] = s;
  adst[i] = d;
}

// ---------------- layer-1 edge kernel: 2 edges/iteration, bf16 gathers ----------------
// lanes 0-31 = edge e, lanes 32-63 = edge e+1. Lane holds channel pair (2*c2, 2*c2+1),
// c2 = lane&31, head h = c2>>2. Final shfl_xor(32) combines halves.

__global__ __launch_bounds__(256) void l1_edge_kernel(const int* __restrict__ row_ptr,
    const int* __restrict__ col, const unsigned int* __restrict__ h1b,
    const float* __restrict__ asrc, const float* __restrict__ adst,
    const float* __restrict__ b1, float* __restrict__ hrelu) {
  int d = (blockIdx.x * blockDim.x + threadIdx.x) >> 6;
  int lane = threadIdx.x & 63;
  if (d >= NN) return;
  int half = lane >> 5, c2 = lane & 31, h = c2 >> 2;
  int start = row_ptr[d], end = row_ptr[d + 1];
  float adst_h = adst[d * 8 + h];
  float ax = 0.f, ay = 0.f, den = 0.f;
  int e = start;
  int n8 = start + ((end - start) & ~7);
  for (; e < n8; e += 8) {      // 4 pairs
    int s[4];
#pragma unroll
    for (int j = 0; j < 4; ++j) s[j] = col[e + 2 * j + half];
    float av[4];
#pragma unroll
    for (int j = 0; j < 4; ++j) av[j] = asrc[s[j] * 8 + h];
    unsigned int hv[4];
#pragma unroll
    for (int j = 0; j < 4; ++j) hv[j] = h1b[(size_t)s[j] * 32 + c2];
#pragma unroll
    for (int j = 0; j < 4; ++j) {
      float a = av[j] + adst_h;
      float logit = a > 0.f ? a : NEG * a;
      float ex = __expf(logit);
      den += ex;
      ax = fmaf(ex, bflo(hv[j]), ax);
      ay = fmaf(ex, bfhi(hv[j]), ay);
    }
  }
  for (; e + 1 < end; e += 2) { // leftover pairs
    int s = col[e + half];
    float a = asrc[s * 8 + h] + adst_h;
    float logit = a > 0.f ? a : NEG * a;
    float ex = __expf(logit);
    unsigned int hv = h1b[(size_t)s * 32 + c2];
    den += ex;
    ax = fmaf(ex, bflo(hv), ax);
    ay = fmaf(ex, bfhi(hv), ay);
  }
  if (e < end) {                // odd tail: half 0 only
    int s = col[e];
    float a = asrc[s * 8 + h] + adst_h;
    float logit = a > 0.f ? a : NEG * a;
    float ex = (half == 0) ? __expf(logit) : 0.f;
    unsigned int hv = h1b[(size_t)s * 32 + c2];
    den += ex;
    ax = fmaf(ex, bflo(hv), ax);
    ay = fmaf(ex, bfhi(hv), ay);
  }
  ax += __shfl_xor(ax, 32);
  ay += __shfl_xor(ay, 32);
  den += __shfl_xor(den, 32);
  if (half == 0) {
    float inv = 1.f / den;
    float o0 = fmaxf(fmaf(ax, inv, 0.f) + b1[2 * c2], 0.f);
    float o1 = fmaxf(fmaf(ay, inv, 0.f) + b1[2 * c2 + 1], 0.f);
    *(float2*)(hrelu + (size_t)d * 64 + 2 * c2) = make_float2(o0, o1);
  }
}

// ---------------- GEMM2: g[N,40] bf16-packed = hrelu[N,64] @ W2[64,40] ----------------

__global__ __launch_bounds__(256) void gemm2_kernel(const float* __restrict__ hrelu,
    const float* __restrict__ W2, unsigned int* __restrict__ gb) {
  __shared__ float w2s[64 * C2N];
  for (int i = threadIdx.x; i < 64 * C2N; i += 256) w2s[i] = W2[i];
  __syncthreads();
  int idx = blockIdx.x * 256 + threadIdx.x;   // idx = n*20 + c2
  if (idx >= NN * 20) return;
  int n = idx / 20;
  int c2 = idx - n * 20;
  const float* hr = hrelu + (size_t)n * 64;
  float a0 = 0.f, a1 = 0.f;
#pragma unroll
  for (int k = 0; k < 64; ++k) {
    float hv = hr[k];
    a0 = fmaf(hv, w2s[k * C2N + 2 * c2], a0);
    a1 = fmaf(hv, w2s[k * C2N + 2 * c2 + 1], a1);
  }
  gb[idx] = pack2bf(a0, a1);
}

// ---------------- layer-2 attention scalars (g packed bf16) ----------------

__global__ __launch_bounds__(256) void att2_kernel(const unsigned int* __restrict__ gb,
    const float* __restrict__ att_src, const float* __restrict__ att_dst,
    float* __restrict__ asrc2, float* __restrict__ adst2) {
  int wv = (blockIdx.x * blockDim.x + threadIdx.x) >> 6;
  int lane = threadIdx.x & 63;
  if (wv >= NN) return;
  float as = 0.f, ad = 0.f;
  if (lane < 20) {
    unsigned int v = gb[(size_t)wv * 20 + lane];
    float f0 = bflo(v), f1 = bfhi(v);
    as = f0 * att_src[2 * lane] + f1 * att_src[2 * lane + 1];
    ad = f0 * att_dst[2 * lane] + f1 * att_dst[2 * lane + 1];
  }
#pragma unroll
  for (int off = 16; off >= 1; off >>= 1) {
    as += __shfl_xor(as, off);
    ad += __shfl_xor(ad, off);
  }
  if (lane == 0) { asrc2[wv] = as; adst2[wv] = ad; }
}

// ---------------- layer-2 edge kernel: 2 edges/iteration, bf16 gathers, log_softmax ----------------
// gb rows are 20 dwords; lanes with c2 in [20,32) read past row end by <=12 dwords
// -> gb allocated with 16-dword slack.

__global__ __launch_bounds__(256) void l2_edge_kernel(const int* __restrict__ row_ptr,
    const int* __restrict__ col, const unsigned int* __restrict__ gb,
    const float* __restrict__ asrc2, const float* __restrict__ adst2,
    const float* __restrict__ b2, float* __restrict__ out) {
  int d = (blockIdx.x * blockDim.x + threadIdx.x) >> 6;
  int lane = threadIdx.x & 63;
  if (d >= NN) return;
  int half = lane >> 5, c2 = lane & 31;
  bool act = c2 < 20;
  int start = row_ptr[d], end = row_ptr[d + 1];
  float adst_d = adst2[d];
  float ax = 0.f, ay = 0.f, den = 0.f;
  int e = start;
  int n8 = start + ((end - start) & ~7);
  for (; e < n8; e += 8) {
    int s[4];
#pragma unroll
    for (int j = 0; j < 4; ++j) s[j] = col[e + 2 * j + half];
    float av[4];
#pragma unroll
    for (int j = 0; j < 4; ++j) av[j] = asrc2[s[j]];
    unsigned int gv[4];
#pragma unroll
    for (int j = 0; j < 4; ++j) gv[j] = gb[(size_t)s[j] * 20 + c2];
#pragma unroll
    for (int j = 0; j < 4; ++j) {
      float a = av[j] + adst_d;
      float logit = a > 0.f ? a : NEG * a;
      float ex = __expf(logit);
      den += ex;
      ax = fmaf(ex, bflo(gv[j]), ax);
      ay = fmaf(ex, bfhi(gv[j]), ay);
    }
  }
  for (; e + 1 < end; e += 2) {
    int s = col[e + half];
    float a = asrc2[s] + adst_d;
    float logit = a > 0.f ? a : NEG * a;
    float ex = __expf(logit);
    unsigned int gv = gb[(size_t)s * 20 + c2];
    den += ex;
    ax = fmaf(ex, bflo(gv), ax);
    ay = fmaf(ex, bfhi(gv), ay);
  }
  if (e < end) {
    int s = col[e];
    float a = asrc2[s] + adst_d;
    float logit = a > 0.f ? a : NEG * a;
    float ex = (half == 0) ? __expf(logit) : 0.f;
    unsigned int gv = gb[(size_t)s * 20 + c2];
    den += ex;
    ax = fmaf(ex, bflo(gv), ax);
    ay = fmaf(ex, bfhi(gv), ay);
  }
  ax += __shfl_xor(ax, 32);
  ay += __shfl_xor(ay, 32);
  den += __shfl_xor(den, 32);
  float inv = 1.f / den;
  float o0 = act ? fmaf(ax, inv, 0.f) + b2[2 * c2]     : 0.f;
  float o1 = act ? fmaf(ay, inv, 0.f) + b2[2 * c2 + 1] : 0.f;
  // log_softmax over 40 values held as 20 lanes x 2 (within each 32-half)
  float m = act ? fmaxf(o0, o1) : -INFINITY;
#pragma unroll
  for (int off = 16; off >= 1; off >>= 1) m = fmaxf(m, __shfl_xor(m, off));
  float es = act ? (__expf(o0 - m) + __expf(o1 - m)) : 0.f;
#pragma unroll
  for (int off = 16; off >= 1; off >>= 1) es += __shfl_xor(es, off);
  float ls = logf(es);
  if (act && half == 0)
    *(float2*)(out + (size_t)d * C2N + 2 * c2) = make_float2(o0 - m - ls, o1 - m - ls);
}

// ---------------- launch ----------------

extern "C" void kernel_launch(void* const* d_in, const int* in_sizes, int n_in,
                              void* d_out, int out_size, void* d_ws, size_t ws_size,
                              hipStream_t stream) {
  const float* x        = (const float*)d_in[0];
  const int*   ei       = (const int*)d_in[1];
  const float* W1       = (const float*)d_in[2];
  const float* att_src1 = (const float*)d_in[3];
  const float* att_dst1 = (const float*)d_in[4];
  const float* b1       = (const float*)d_in[5];
  const float* W2       = (const float*)d_in[6];
  const float* att_src2 = (const float*)d_in[7];
  const float* att_dst2 = (const float*)d_in[8];
  const float* b2       = (const float*)d_in[9];
  float* out = (float*)d_out;

  char* ws = (char*)d_ws;
  size_t off = 0;
  auto alloc = [&](size_t n_elem) {
    void* p = ws + off;
    off = (off + n_elem * 4 + 255) & ~(size_t)255;
    return p;
  };
  unsigned int* h1b = (unsigned int*)alloc((size_t)NN * 32);      // bf16 packed [N][32]
  float* hrelu = (float*)alloc((size_t)NN * 64);                  // also aliased as bucket_glob
  unsigned int* gb  = (unsigned int*)alloc((size_t)NN * 20 + 16); // bf16 packed [N][20] + slack
  float* asrc1 = (float*)alloc((size_t)NN * 8);
  float* adst1 = (float*)alloc((size_t)NN * 8);
  float* asrc2 = (float*)alloc(NN);
  float* adst2 = (float*)alloc(NN);
  int* row_ptr = (int*)alloc(NN + 1);
  int* colv    = (int*)alloc(EE + NN);
  int* bucket_cnt  = (int*)alloc(NB);
  int* bucket_base = (int*)alloc(NB);
  short* w1t   = (short*)alloc(64 * 512 / 2);
  unsigned int* bucket_glob = (unsigned int*)hrelu;  // consumed by passB before hrelu written

  hipMemsetAsync(bucket_cnt, 0, NB * 4, stream);
  passA_kernel<<<PA_BLOCKS, 256, 0, stream>>>(ei, bucket_cnt, bucket_glob);
  scan_buckets<<<1, 512, 0, stream>>>(bucket_cnt, bucket_base, row_ptr + NN);
  passB_kernel<<<NB, 256, 0, stream>>>(bucket_glob, bucket_cnt, bucket_base, row_ptr, colv);

  w1t_kernel<<<(64 * 512 + 255) / 256, 256, 0, stream>>>(W1, w1t);
  gemm1_kernel<<<(NN + 63) / 64, 256, 0, stream>>>(x, w1t, (unsigned short*)h1b);
  att1_kernel<<<(NN * 8 + 255) / 256, 256, 0, stream>>>(h1b, att_src1, att_dst1, asrc1, adst1);
  l1_edge_kernel<<<(NN * 64 + 255) / 256, 256, 0, stream>>>(row_ptr, colv, h1b, asrc1, adst1, b1, hrelu);

  gemm2_kernel<<<(NN * 20 + 255) / 256, 256, 0, stream>>>(hrelu, W2, gb);
  att2_kernel<<<(NN * 64 + 255) / 256, 256, 0, stream>>>(gb, att_src2, att_dst2, asrc2, adst2);
  l2_edge_kernel<<<(NN * 64 + 255) / 256, 256, 0, stream>>>(row_ptr, colv, gb, asrc2, adst2, b2, out);
}

// Round 7
// 360.105 us; speedup vs baseline: 1.7624x; 1.0214x over previous
//
#include <hip/hip_runtime.h>
#include <math.h>

#define NN 50000
#define EE 1600000
#define FIN 512
#define H1N 8
#define C2N 40
#define NEG 0.2f

// ---------------- bucketed CSR build ----------------
#define NB 391
#define CAPG 6144
#define PA_ITEMS 8192
#define NITEMS (EE + NN)
#define PA_BLOCKS ((NITEMS + PA_ITEMS - 1) / PA_ITEMS)   // 202
#define W1T_BLOCKS 32

// bf16 helpers
typedef __attribute__((ext_vector_type(8))) short bf16x8;
typedef __attribute__((ext_vector_type(4))) float f32x4;

__device__ inline short f2bf(float f) {
  unsigned int u = __float_as_uint(f);
  u += 0x7FFFu + ((u >> 16) & 1u);     // round-to-nearest-even
  return (short)(u >> 16);
}
__device__ inline unsigned int pack2bf(float lo, float hi) {
  return (unsigned int)(unsigned short)f2bf(lo) | ((unsigned int)(unsigned short)f2bf(hi) << 16);
}
__device__ inline float bflo(unsigned int v) { return __uint_as_float(v << 16); }
__device__ inline float bfhi(unsigned int v) { return __uint_as_float(v & 0xFFFF0000u); }

// passA: coarse binning with LDS staging; w1t transpose folded in as extra blocks.
__global__ __launch_bounds__(256) void passA_kernel(const int* __restrict__ ei,
    int* __restrict__ bucket_cnt, unsigned int* __restrict__ bucket_glob,
    const float* __restrict__ W1, short* __restrict__ WT) {
  int t = threadIdx.x;
  if (blockIdx.x >= PA_BLOCKS) {
    // W1 [512][64] -> WT bf16 [64][512]; 32 blocks x 1024 elements
    int base = (blockIdx.x - PA_BLOCKS) * 1024 + t * 4;
#pragma unroll
    for (int j = 0; j < 4; ++j) {
      int i = base + j;                   // i = n*512 + k
      int n = i >> 9, k = i & 511;
      WT[i] = f2bf(W1[k * 64 + n]);
    }
    return;
  }
  __shared__ int hist[NB];
  __shared__ int prefix[NB];
  __shared__ int cursor[NB];
  __shared__ int gbase[NB];
  __shared__ int scA[512], scB[512];
  __shared__ unsigned int staging[PA_ITEMS];
  int i0 = blockIdx.x * PA_ITEMS;
  int count = NITEMS - i0; if (count > PA_ITEMS) count = PA_ITEMS;

  for (int b = t; b < NB; b += 256) hist[b] = 0;
  __syncthreads();
  for (int j = t; j < count; j += 256) {
    int e = i0 + j;
    int dst = (e < EE) ? ei[EE + e] : (e - EE);
    atomicAdd(&hist[dst >> 7], 1);
  }
  __syncthreads();
  scA[t]       = (t < NB) ? hist[t] : 0;
  scA[t + 256] = (t + 256 < NB) ? hist[t + 256] : 0;
  __syncthreads();
  {
    int* pa = scA; int* pb = scB;
    for (int off = 1; off < 512; off <<= 1) {
      pb[t]       = pa[t]       + (t >= off ? pa[t - off] : 0);
      pb[t + 256] = pa[t + 256] + (t + 256 >= off ? pa[t + 256 - off] : 0);
      __syncthreads();
      int* tmp = pa; pa = pb; pb = tmp;
    }
    for (int b = t; b < NB; b += 256) {
      int ex = pa[b] - hist[b];
      prefix[b] = ex;
      cursor[b] = ex;
      if (hist[b] > 0) gbase[b] = atomicAdd(&bucket_cnt[b], hist[b]);
    }
  }
  __syncthreads();
  for (int j = t; j < count; j += 256) {
    int e = i0 + j;
    int src, dst;
    if (e < EE) { src = ei[e]; dst = ei[EE + e]; }
    else        { src = e - EE; dst = src; }
    int b = dst >> 7;
    unsigned int v = (unsigned int)src | ((unsigned int)(dst & 127) << 16)
                   | ((unsigned int)b << 23);
    int lp = atomicAdd(&cursor[b], 1);
    staging[lp] = v;
  }
  __syncthreads();
  for (int j = t; j < count; j += 256) {
    unsigned int v = staging[j];
    int b = (int)(v >> 23);
    int gpos = b * CAPG + gbase[b] + (j - prefix[b]);
    bucket_glob[gpos] = v;
  }
}

__global__ __launch_bounds__(512) void scan_buckets(const int* __restrict__ bucket_cnt,
    int* __restrict__ bucket_base, int* __restrict__ row_ptr_last) {
  __shared__ int scA[512], scB[512];
  int t = threadIdx.x;
  int v = (t < NB) ? bucket_cnt[t] : 0;
  scA[t] = v;
  __syncthreads();
  int* pa = scA; int* pb = scB;
  for (int off = 1; off < 512; off <<= 1) {
    pb[t] = pa[t] + (t >= off ? pa[t - off] : 0);
    __syncthreads();
    int* tmp = pa; pa = pb; pb = tmp;
  }
  if (t < NB) bucket_base[t] = pa[t] - v;
  if (t == NB - 1) *row_ptr_last = pa[t];
}

#define CAPB 6144
__global__ __launch_bounds__(256) void passB_kernel(const unsigned int* __restrict__ bucket_glob,
    const int* __restrict__ bucket_cnt, const int* __restrict__ bucket_base,
    int* __restrict__ row_ptr, int* __restrict__ col) {
  __shared__ int hist[128], pre[128], cur[128];
  __shared__ int scA[128], scB[128];
  __shared__ int sorted[CAPB];
  int b = blockIdx.x, t = threadIdx.x;
  int cnt = bucket_cnt[b];
  int base = bucket_base[b];
  const unsigned int* in = bucket_glob + (size_t)b * CAPG;
  if (t < 128) hist[t] = 0;
  __syncthreads();
  for (int j = t; j < cnt; j += 256) {
    int dl = (int)((in[j] >> 16) & 127u);
    atomicAdd(&hist[dl], 1);
  }
  __syncthreads();
  if (t < 128) scA[t] = hist[t];
  __syncthreads();
  {
    int* pa = scA; int* pb = scB;
    for (int off = 1; off < 128; off <<= 1) {
      if (t < 128) pb[t] = pa[t] + (t >= off ? pa[t - off] : 0);
      __syncthreads();
      int* tmp = pa; pa = pb; pb = tmp;
    }
    if (t < 128) {
      int ex = pa[t] - hist[t];
      pre[t] = ex;
      cur[t] = ex;
      int d = b * 128 + t;
      if (d < NN) row_ptr[d] = base + ex;
    }
  }
  __syncthreads();
  for (int j = t; j < cnt; j += 256) {
    unsigned int v = in[j];
    int dl = (int)((v >> 16) & 127u);
    int lp = atomicAdd(&cur[dl], 1);
    sorted[lp] = (int)(v & 0xFFFFu);
  }
  __syncthreads();
  for (int j = t; j < cnt; j += 256) col[base + j] = sorted[j];
}

// ---------------- GEMM1 (bf16 MFMA) + fused att1 ----------------
// h1[N,64] = x[N,512] @ W1[512,64]; h1 stored packed bf16 [N][32 dwords].
// Epilogue: f32 tile staged to LDS (stride 68 -> 16B aligned), 256 threads
// compute asrc1/adst1 = per-(row,head) dots with att vectors.

#define XS_STRIDE 136
#define HS_STRIDE 68
__global__ __launch_bounds__(256) void gemm1_kernel(const float* __restrict__ x,
    const short* __restrict__ WT, unsigned short* __restrict__ h1b,
    const float* __restrict__ att_src, const float* __restrict__ att_dst,
    float* __restrict__ asrc, float* __restrict__ adst) {
  __shared__ char smem[64 * XS_STRIDE * 2];   // 17408 B; aliased short/float
  short* xs = (short*)smem;
  float* hsf = (float*)smem;                  // 64 x HS_STRIDE floats = 17408 B
  int t = threadIdx.x;
  int wave = t >> 6, lane = t & 63;
  int quad = lane >> 4, m = lane & 15;
  int row0 = blockIdx.x * 64;
  f32x4 acc[4] = {{0.f,0.f,0.f,0.f},{0.f,0.f,0.f,0.f},{0.f,0.f,0.f,0.f},{0.f,0.f,0.f,0.f}};
  for (int kc = 0; kc < 4; ++kc) {
    int k0 = kc * 128;
    __syncthreads();
#pragma unroll
    for (int jj = 0; jj < 8; ++jj) {
      int idx = jj * 256 + t;
      int row = idx >> 5, kq = idx & 31;
      int rr = row0 + row; if (rr >= NN) rr = NN - 1;
      float4 v = *(const float4*)(x + (size_t)rr * FIN + k0 + kq * 4);
      short4 s;
      s.x = f2bf(v.x); s.y = f2bf(v.y); s.z = f2bf(v.z); s.w = f2bf(v.w);
      *(short4*)&xs[row * XS_STRIDE + kq * 4] = s;
    }
    __syncthreads();
#pragma unroll
    for (int ks = 0; ks < 4; ++ks) {
      bf16x8 a = *(bf16x8*)&xs[(wave * 16 + m) * XS_STRIDE + ks * 32 + quad * 8];
#pragma unroll
      for (int tl = 0; tl < 4; ++tl) {
        bf16x8 b = *(const bf16x8*)(WT + (size_t)(tl * 16 + m) * 512 + k0 + ks * 32 + quad * 8);
        acc[tl] = __builtin_amdgcn_mfma_f32_16x16x32_bf16(a, b, acc[tl], 0, 0, 0);
      }
    }
  }
  // epilogue: global bf16 store + LDS f32 stage
  __syncthreads();   // all waves done reading xs
  int rl0 = wave * 16 + quad * 4;
#pragma unroll
  for (int tl = 0; tl < 4; ++tl) {
#pragma unroll
    for (int r = 0; r < 4; ++r) {
      int rr = row0 + rl0 + r;
      if (rr < NN) h1b[(size_t)rr * 64 + tl * 16 + m] = (unsigned short)f2bf(acc[tl][r]);
      hsf[(rl0 + r) * HS_STRIDE + tl * 16 + m] = acc[tl][r];
    }
  }
  __syncthreads();
  // fused att1: 512 (row,head) pairs over 256 threads
#pragma unroll
  for (int p = 0; p < 2; ++p) {
    int idx = p * 256 + t;
    int rl = idx >> 3, h = idx & 7;
    int rr = row0 + rl;
    if (rr < NN) {
      const float* hv = &hsf[rl * HS_STRIDE + h * 8];
      const float* as = att_src + h * 8;
      const float* ad = att_dst + h * 8;
      float s = 0.f, dd = 0.f;
#pragma unroll
      for (int c = 0; c < 8; ++c) { s = fmaf(hv[c], as[c], s); dd = fmaf(hv[c], ad[c], dd); }
      asrc[rr * 8 + h] = s;
      adst[rr * 8 + h] = dd;
    }
  }
}

// ---------------- layer-1 edge kernel + fused gemm2 + att2 ----------------
// 2 edges/iteration (halves of the wave), bf16 h1 gathers. Epilogue: hrelu row
// staged per-wave in LDS; lane c<40 computes g[c] (64 FMA vs LDS-broadcast
// hrelu and LDS W2); wave-reduce asrc2/adst2; pack gb bf16.

__global__ __launch_bounds__(256) void l1_edge_kernel(const int* __restrict__ row_ptr,
    const int* __restrict__ col, const unsigned int* __restrict__ h1b,
    const float* __restrict__ asrc, const float* __restrict__ adst,
    const float* __restrict__ b1, const float* __restrict__ W2,
    const float* __restrict__ att_src2, const float* __restrict__ att_dst2,
    unsigned int* __restrict__ gb, float* __restrict__ asrc2, float* __restrict__ adst2) {
  __shared__ float w2s[64 * C2N];    // 10240 B
  __shared__ float hs[4][64];
  __shared__ float gs[4][48];
  int t = threadIdx.x;
  for (int i = t; i < 64 * C2N; i += 256) w2s[i] = W2[i];
  __syncthreads();
  int d = (blockIdx.x * 256 + t) >> 6;       // grid sized exactly: d < NN
  int lane = t & 63;
  int wave = t >> 6;
  int half = lane >> 5, c2 = lane & 31, h = c2 >> 2;
  int start = row_ptr[d], end = row_ptr[d + 1];
  float adst_h = adst[d * 8 + h];
  float ax = 0.f, ay = 0.f, den = 0.f;
  int e = start;
  int n8 = start + ((end - start) & ~7);
  for (; e < n8; e += 8) {      // 4 pairs
    int s[4];
#pragma unroll
    for (int j = 0; j < 4; ++j) s[j] = col[e + 2 * j + half];
    float av[4];
#pragma unroll
    for (int j = 0; j < 4; ++j) av[j] = asrc[s[j] * 8 + h];
    unsigned int hv[4];
#pragma unroll
    for (int j = 0; j < 4; ++j) hv[j] = h1b[(size_t)s[j] * 32 + c2];
#pragma unroll
    for (int j = 0; j < 4; ++j) {
      float a = av[j] + adst_h;
      float logit = a > 0.f ? a : NEG * a;
      float ex = __expf(logit);
      den += ex;
      ax = fmaf(ex, bflo(hv[j]), ax);
      ay = fmaf(ex, bfhi(hv[j]), ay);
    }
  }
  for (; e + 1 < end; e += 2) {
    int s = col[e + half];
    float a = asrc[s * 8 + h] + adst_h;
    float logit = a > 0.f ? a : NEG * a;
    float ex = __expf(logit);
    unsigned int hv = h1b[(size_t)s * 32 + c2];
    den += ex;
    ax = fmaf(ex, bflo(hv), ax);
    ay = fmaf(ex, bfhi(hv), ay);
  }
  if (e < end) {
    int s = col[e];
    float a = asrc[s * 8 + h] + adst_h;
    float logit = a > 0.f ? a : NEG * a;
    float ex = (half == 0) ? __expf(logit) : 0.f;
    unsigned int hv = h1b[(size_t)s * 32 + c2];
    den += ex;
    ax = fmaf(ex, bflo(hv), ax);
    ay = fmaf(ex, bfhi(hv), ay);
  }
  ax += __shfl_xor(ax, 32);
  ay += __shfl_xor(ay, 32);
  den += __shfl_xor(den, 32);
  if (half == 0) {
    float inv = 1.f / den;
    float o0 = fmaxf(fmaf(ax, inv, 0.f) + b1[2 * c2], 0.f);
    float o1 = fmaxf(fmaf(ay, inv, 0.f) + b1[2 * c2 + 1], 0.f);
    hs[wave][2 * c2]     = o0;
    hs[wave][2 * c2 + 1] = o1;
  }
  // fused gemm2: lane c computes g[c]  (within-wave LDS, no barrier needed)
  int c = lane;
  float gacc = 0.f;
  if (c < C2N) {
#pragma unroll
    for (int k = 0; k < 64; ++k) gacc = fmaf(hs[wave][k], w2s[k * C2N + c], gacc);
  }
  // fused att2: wave reduction
  float asv = (c < C2N) ? gacc * att_src2[c] : 0.f;
  float adv = (c < C2N) ? gacc * att_dst2[c] : 0.f;
#pragma unroll
  for (int off = 32; off >= 1; off >>= 1) {
    asv += __shfl_xor(asv, off);
    adv += __shfl_xor(adv, off);
  }
  if (lane == 0) { asrc2[d] = asv; adst2[d] = adv; }
  if (c < C2N) gs[wave][c] = gacc;
  if (lane < 20) gb[(size_t)d * 20 + lane] = pack2bf(gs[wave][2 * lane], gs[wave][2 * lane + 1]);
}

// ---------------- layer-2 edge kernel: 2 edges/iteration, log_softmax ----------------

__global__ __launch_bounds__(256) void l2_edge_kernel(const int* __restrict__ row_ptr,
    const int* __restrict__ col, const unsigned int* __restrict__ gb,
    const float* __restrict__ asrc2, const float* __restrict__ adst2,
    const float* __restrict__ b2, float* __restrict__ out) {
  int d = (blockIdx.x * blockDim.x + threadIdx.x) >> 6;
  int lane = threadIdx.x & 63;
  if (d >= NN) return;
  int half = lane >> 5, c2 = lane & 31;
  bool act = c2 < 20;
  int cL = act ? c2 : 19;    // clamp: garbage lanes re-read in-row (no 3rd line)
  int start = row_ptr[d], end = row_ptr[d + 1];
  float adst_d = adst2[d];
  float ax = 0.f, ay = 0.f, den = 0.f;
  int e = start;
  int n8 = start + ((end - start) & ~7);
  for (; e < n8; e += 8) {
    int s[4];
#pragma unroll
    for (int j = 0; j < 4; ++j) s[j] = col[e + 2 * j + half];
    float av[4];
#pragma unroll
    for (int j = 0; j < 4; ++j) av[j] = asrc2[s[j]];
    unsigned int gv[4];
#pragma unroll
    for (int j = 0; j < 4; ++j) gv[j] = gb[(size_t)s[j] * 20 + cL];
#pragma unroll
    for (int j = 0; j < 4; ++j) {
      float a = av[j] + adst_d;
      float logit = a > 0.f ? a : NEG * a;
      float ex = __expf(logit);
      den += ex;
      ax = fmaf(ex, bflo(gv[j]), ax);
      ay = fmaf(ex, bfhi(gv[j]), ay);
    }
  }
  for (; e + 1 < end; e += 2) {
    int s = col[e + half];
    float a = asrc2[s] + adst_d;
    float logit = a > 0.f ? a : NEG * a;
    float ex = __expf(logit);
    unsigned int gv = gb[(size_t)s * 20 + cL];
    den += ex;
    ax = fmaf(ex, bflo(gv), ax);
    ay = fmaf(ex, bfhi(gv), ay);
  }
  if (e < end) {
    int s = col[e];
    float a = asrc2[s] + adst_d;
    float logit = a > 0.f ? a : NEG * a;
    float ex = (half == 0) ? __expf(logit) : 0.f;
    unsigned int gv = gb[(size_t)s * 20 + cL];
    den += ex;
    ax = fmaf(ex, bflo(gv), ax);
    ay = fmaf(ex, bfhi(gv), ay);
  }
  ax += __shfl_xor(ax, 32);
  ay += __shfl_xor(ay, 32);
  den += __shfl_xor(den, 32);
  float inv = 1.f / den;
  float o0 = act ? fmaf(ax, inv, 0.f) + b2[2 * c2]     : 0.f;
  float o1 = act ? fmaf(ay, inv, 0.f) + b2[2 * c2 + 1] : 0.f;
  float m = act ? fmaxf(o0, o1) : -INFINITY;
#pragma unroll
  for (int off = 16; off >= 1; off >>= 1) m = fmaxf(m, __shfl_xor(m, off));
  float es = act ? (__expf(o0 - m) + __expf(o1 - m)) : 0.f;
#pragma unroll
  for (int off = 16; off >= 1; off >>= 1) es += __shfl_xor(es, off);
  float ls = logf(es);
  if (act && half == 0)
    *(float2*)(out + (size_t)d * C2N + 2 * c2) = make_float2(o0 - m - ls, o1 - m - ls);
}

// ---------------- launch ----------------

extern "C" void kernel_launch(void* const* d_in, const int* in_sizes, int n_in,
                              void* d_out, int out_size, void* d_ws, size_t ws_size,
                              hipStream_t stream) {
  const float* x        = (const float*)d_in[0];
  const int*   ei       = (const int*)d_in[1];
  const float* W1       = (const float*)d_in[2];
  const float* att_src1 = (const float*)d_in[3];
  const float* att_dst1 = (const float*)d_in[4];
  const float* b1       = (const float*)d_in[5];
  const float* W2       = (const float*)d_in[6];
  const float* att_src2 = (const float*)d_in[7];
  const float* att_dst2 = (const float*)d_in[8];
  const float* b2       = (const float*)d_in[9];
  float* out = (float*)d_out;

  char* ws = (char*)d_ws;
  size_t off = 0;
  auto alloc = [&](size_t n_elem) {
    void* p = ws + off;
    off = (off + n_elem * 4 + 255) & ~(size_t)255;
    return p;
  };
  unsigned int* h1b = (unsigned int*)alloc((size_t)NN * 32);      // bf16 packed [N][32]
  unsigned int* gb  = (unsigned int*)alloc((size_t)NN * 20 + 16); // bf16 packed [N][20] + slack
  unsigned int* bucket_glob = (unsigned int*)alloc((size_t)NB * CAPG);
  float* asrc1 = (float*)alloc((size_t)NN * 8);
  float* adst1 = (float*)alloc((size_t)NN * 8);
  float* asrc2 = (float*)alloc(NN);
  float* adst2 = (float*)alloc(NN);
  int* row_ptr = (int*)alloc(NN + 1);
  int* colv    = (int*)alloc(EE + NN);
  int* bucket_cnt  = (int*)alloc(NB);
  int* bucket_base = (int*)alloc(NB);
  short* w1t   = (short*)alloc(64 * 512 / 2);

  hipMemsetAsync(bucket_cnt, 0, NB * 4, stream);
  passA_kernel<<<PA_BLOCKS + W1T_BLOCKS, 256, 0, stream>>>(ei, bucket_cnt, bucket_glob, W1, w1t);
  scan_buckets<<<1, 512, 0, stream>>>(bucket_cnt, bucket_base, row_ptr + NN);
  passB_kernel<<<NB, 256, 0, stream>>>(bucket_glob, bucket_cnt, bucket_base, row_ptr, colv);

  gemm1_kernel<<<(NN + 63) / 64, 256, 0, stream>>>(x, w1t, (unsigned short*)h1b,
                                                   att_src1, att_dst1, asrc1, adst1);
  l1_edge_kernel<<<(NN * 64 + 255) / 256, 256, 0, stream>>>(row_ptr, colv, h1b, asrc1, adst1,
                                                            b1, W2, att_src2, att_dst2,
                                                            gb, asrc2, adst2);
  l2_edge_kernel<<<(NN * 64 + 255) / 256, 256, 0, stream>>>(row_ptr, colv, gb, asrc2, adst2, b2, out);
}

// Round 8
// 329.719 us; speedup vs baseline: 1.9248x; 1.0922x over previous
//
#include <hip/hip_runtime.h>
#include <math.h>

#define NN 50000
#define EE 1600000
#define FIN 512
#define H1N 8
#define C2N 40
#define NEG 0.2f

// ---------------- bucketed CSR build ----------------
#define NB 391
#define CAPG 6144
#define PA_ITEMS 4096
#define NITEMS (EE + NN)
#define PA_BLOCKS ((NITEMS + PA_ITEMS - 1) / PA_ITEMS)   // 403
#define W1T_BLOCKS 32

// bf16 helpers
typedef __attribute__((ext_vector_type(8))) short bf16x8;
typedef __attribute__((ext_vector_type(4))) float f32x4;

__device__ inline short f2bf(float f) {
  unsigned int u = __float_as_uint(f);
  u += 0x7FFFu + ((u >> 16) & 1u);     // round-to-nearest-even
  return (short)(u >> 16);
}
__device__ inline unsigned int pack2bf(float lo, float hi) {
  return (unsigned int)(unsigned short)f2bf(lo) | ((unsigned int)(unsigned short)f2bf(hi) << 16);
}
__device__ inline float bflo(unsigned int v) { return __uint_as_float(v << 16); }
__device__ inline float bfhi(unsigned int v) { return __uint_as_float(v & 0xFFFF0000u); }

// passA: coarse binning with LDS staging; w1t transpose folded in as extra blocks.
__global__ __launch_bounds__(256) void passA_kernel(const int* __restrict__ ei,
    int* __restrict__ bucket_cnt, unsigned int* __restrict__ bucket_glob,
    const float* __restrict__ W1, short* __restrict__ WT) {
  int t = threadIdx.x;
  if (blockIdx.x >= PA_BLOCKS) {
    int base = (blockIdx.x - PA_BLOCKS) * 1024 + t * 4;
#pragma unroll
    for (int j = 0; j < 4; ++j) {
      int i = base + j;                   // i = n*512 + k
      int n = i >> 9, k = i & 511;
      WT[i] = f2bf(W1[k * 64 + n]);
    }
    return;
  }
  __shared__ int hist[NB];
  __shared__ int prefix[NB];
  __shared__ int cursor[NB];
  __shared__ int gbase[NB];
  __shared__ int scA[512], scB[512];
  __shared__ unsigned int staging[PA_ITEMS];
  int i0 = blockIdx.x * PA_ITEMS;
  int count = NITEMS - i0; if (count > PA_ITEMS) count = PA_ITEMS;

  for (int b = t; b < NB; b += 256) hist[b] = 0;
  __syncthreads();
  for (int j = t; j < count; j += 256) {
    int e = i0 + j;
    int dst = (e < EE) ? ei[EE + e] : (e - EE);
    atomicAdd(&hist[dst >> 7], 1);
  }
  __syncthreads();
  scA[t]       = (t < NB) ? hist[t] : 0;
  scA[t + 256] = (t + 256 < NB) ? hist[t + 256] : 0;
  __syncthreads();
  {
    int* pa = scA; int* pb = scB;
    for (int off = 1; off < 512; off <<= 1) {
      pb[t]       = pa[t]       + (t >= off ? pa[t - off] : 0);
      pb[t + 256] = pa[t + 256] + (t + 256 >= off ? pa[t + 256 - off] : 0);
      __syncthreads();
      int* tmp = pa; pa = pb; pb = tmp;
    }
    for (int b = t; b < NB; b += 256) {
      int ex = pa[b] - hist[b];
      prefix[b] = ex;
      cursor[b] = ex;
      if (hist[b] > 0) gbase[b] = atomicAdd(&bucket_cnt[b], hist[b]);
    }
  }
  __syncthreads();
  for (int j = t; j < count; j += 256) {
    int e = i0 + j;
    int src, dst;
    if (e < EE) { src = ei[e]; dst = ei[EE + e]; }
    else        { src = e - EE; dst = src; }
    int b = dst >> 7;
    unsigned int v = (unsigned int)src | ((unsigned int)(dst & 127) << 16)
                   | ((unsigned int)b << 23);
    int lp = atomicAdd(&cursor[b], 1);
    staging[lp] = v;
  }
  __syncthreads();
  for (int j = t; j < count; j += 256) {
    unsigned int v = staging[j];
    int b = (int)(v >> 23);
    int gpos = b * CAPG + gbase[b] + (j - prefix[b]);
    bucket_glob[gpos] = v;
  }
}

__global__ __launch_bounds__(512) void scan_buckets(const int* __restrict__ bucket_cnt,
    int* __restrict__ bucket_base, int* __restrict__ row_ptr_last) {
  __shared__ int scA[512], scB[512];
  int t = threadIdx.x;
  int v = (t < NB) ? bucket_cnt[t] : 0;
  scA[t] = v;
  __syncthreads();
  int* pa = scA; int* pb = scB;
  for (int off = 1; off < 512; off <<= 1) {
    pb[t] = pa[t] + (t >= off ? pa[t - off] : 0);
    __syncthreads();
    int* tmp = pa; pa = pb; pb = tmp;
  }
  if (t < NB) bucket_base[t] = pa[t] - v;
  if (t == NB - 1) *row_ptr_last = pa[t];
}

#define CAPB 6144
__global__ __launch_bounds__(256) void passB_kernel(const unsigned int* __restrict__ bucket_glob,
    const int* __restrict__ bucket_cnt, const int* __restrict__ bucket_base,
    int* __restrict__ row_ptr, int* __restrict__ col) {
  __shared__ int hist[128], pre[128], cur[128];
  __shared__ int scA[128], scB[128];
  __shared__ int sorted[CAPB];
  int b = blockIdx.x, t = threadIdx.x;
  int cnt = bucket_cnt[b];
  int base = bucket_base[b];
  const unsigned int* in = bucket_glob + (size_t)b * CAPG;
  if (t < 128) hist[t] = 0;
  __syncthreads();
  for (int j = t; j < cnt; j += 256) {
    int dl = (int)((in[j] >> 16) & 127u);
    atomicAdd(&hist[dl], 1);
  }
  __syncthreads();
  if (t < 128) scA[t] = hist[t];
  __syncthreads();
  {
    int* pa = scA; int* pb = scB;
    for (int off = 1; off < 128; off <<= 1) {
      if (t < 128) pb[t] = pa[t] + (t >= off ? pa[t - off] : 0);
      __syncthreads();
      int* tmp = pa; pa = pb; pb = tmp;
    }
    if (t < 128) {
      int ex = pa[t] - hist[t];
      pre[t] = ex;
      cur[t] = ex;
      int d = b * 128 + t;
      if (d < NN) row_ptr[d] = base + ex;
    }
  }
  __syncthreads();
  for (int j = t; j < cnt; j += 256) {
    unsigned int v = in[j];
    int dl = (int)((v >> 16) & 127u);
    int lp = atomicAdd(&cur[dl], 1);
    sorted[lp] = (int)(v & 0xFFFFu);
  }
  __syncthreads();
  for (int j = t; j < cnt; j += 256) col[base + j] = sorted[j];
}

// ---------------- GEMM1 (bf16 MFMA) + fused att1 ----------------

#define XS_STRIDE 136
#define HS_STRIDE 68
__global__ __launch_bounds__(256) void gemm1_kernel(const float* __restrict__ x,
    const short* __restrict__ WT, unsigned short* __restrict__ h1b,
    const float* __restrict__ att_src, const float* __restrict__ att_dst,
    float* __restrict__ asrc, float* __restrict__ adst) {
  __shared__ char smem[64 * XS_STRIDE * 2];   // 17408 B; aliased short/float
  short* xs = (short*)smem;
  float* hsf = (float*)smem;
  int t = threadIdx.x;
  int wave = t >> 6, lane = t & 63;
  int quad = lane >> 4, m = lane & 15;
  int row0 = blockIdx.x * 64;
  f32x4 acc[4] = {{0.f,0.f,0.f,0.f},{0.f,0.f,0.f,0.f},{0.f,0.f,0.f,0.f},{0.f,0.f,0.f,0.f}};
  for (int kc = 0; kc < 4; ++kc) {
    int k0 = kc * 128;
    __syncthreads();
#pragma unroll
    for (int jj = 0; jj < 8; ++jj) {
      int idx = jj * 256 + t;
      int row = idx >> 5, kq = idx & 31;
      int rr = row0 + row; if (rr >= NN) rr = NN - 1;
      float4 v = *(const float4*)(x + (size_t)rr * FIN + k0 + kq * 4);
      short4 s;
      s.x = f2bf(v.x); s.y = f2bf(v.y); s.z = f2bf(v.z); s.w = f2bf(v.w);
      *(short4*)&xs[row * XS_STRIDE + kq * 4] = s;
    }
    __syncthreads();
#pragma unroll
    for (int ks = 0; ks < 4; ++ks) {
      bf16x8 a = *(bf16x8*)&xs[(wave * 16 + m) * XS_STRIDE + ks * 32 + quad * 8];
#pragma unroll
      for (int tl = 0; tl < 4; ++tl) {
        bf16x8 b = *(const bf16x8*)(WT + (size_t)(tl * 16 + m) * 512 + k0 + ks * 32 + quad * 8);
        acc[tl] = __builtin_amdgcn_mfma_f32_16x16x32_bf16(a, b, acc[tl], 0, 0, 0);
      }
    }
  }
  __syncthreads();
  int rl0 = wave * 16 + quad * 4;
#pragma unroll
  for (int tl = 0; tl < 4; ++tl) {
#pragma unroll
    for (int r = 0; r < 4; ++r) {
      int rr = row0 + rl0 + r;
      if (rr < NN) h1b[(size_t)rr * 64 + tl * 16 + m] = (unsigned short)f2bf(acc[tl][r]);
      hsf[(rl0 + r) * HS_STRIDE + tl * 16 + m] = acc[tl][r];
    }
  }
  __syncthreads();
#pragma unroll
  for (int p = 0; p < 2; ++p) {
    int idx = p * 256 + t;
    int rl = idx >> 3, h = idx & 7;
    int rr = row0 + rl;
    if (rr < NN) {
      const float* hv = &hsf[rl * HS_STRIDE + h * 8];
      const float* as = att_src + h * 8;
      const float* ad = att_dst + h * 8;
      float s = 0.f, dd = 0.f;
#pragma unroll
      for (int c = 0; c < 8; ++c) { s = fmaf(hv[c], as[c], s); dd = fmaf(hv[c], ad[c], dd); }
      asrc[rr * 8 + h] = s;
      adst[rr * 8 + h] = dd;
    }
  }
}

// ---------------- layer-1 edge kernel (8 edges/iter, uint4 gathers) + fused gemm2/att2 ----------------
// lane = (j = lane>>3 edge slot, g = lane&7). Lane covers channels 8g..8g+7 = head g:
// per 8 edges just 3 VMEM (col dword, asrc dword, h1b dwordx4). Unroll x2 = 16 edges.
// shfl_xor(8/16/32) reduction leaves totals in ALL lanes -> epilogue unchanged.
// Block handles 16 dsts (4 iters) to amortize the W2 LDS preload.

__global__ __launch_bounds__(256) void l1_edge_kernel(const int* __restrict__ row_ptr,
    const int* __restrict__ col, const unsigned int* __restrict__ h1b,
    const float* __restrict__ asrc, const float* __restrict__ adst,
    const float* __restrict__ b1, const float* __restrict__ W2,
    const float* __restrict__ att_src2, const float* __restrict__ att_dst2,
    unsigned int* __restrict__ gb, float* __restrict__ asrc2, float* __restrict__ adst2) {
  __shared__ float w2s[64 * C2N];    // 10240 B
  __shared__ float hs[4][64];
  __shared__ float gs[4][48];
  int t = threadIdx.x;
  for (int i = t; i < 64 * C2N; i += 256) w2s[i] = W2[i];
  __syncthreads();
  int wave = t >> 6, lane = t & 63;
  int g = lane & 7, j = lane >> 3;
#pragma unroll 1
  for (int iter = 0; iter < 4; ++iter) {
    int d = blockIdx.x * 16 + iter * 4 + wave;
    if (d >= NN) break;                    // no barriers below: safe divergence
    int start = row_ptr[d], end = row_ptr[d + 1];
    float adst_h = adst[d * 8 + g];
    float acc[8] = {0.f,0.f,0.f,0.f,0.f,0.f,0.f,0.f};
    float den = 0.f;
    for (int e = start; e < end; e += 16) {
      int i1 = e + j, i2 = e + 8 + j;
      int k1 = i1 < end ? i1 : end - 1;
      int k2 = i2 < end ? i2 : end - 1;
      int s1 = col[k1], s2 = col[k2];
      float av1 = asrc[s1 * 8 + g];
      float av2 = asrc[s2 * 8 + g];
      uint4 hv1 = *(const uint4*)(h1b + (size_t)s1 * 32 + g * 4);
      uint4 hv2 = *(const uint4*)(h1b + (size_t)s2 * 32 + g * 4);
      float a1 = av1 + adst_h, a2 = av2 + adst_h;
      float lg1 = fmaxf(a1, NEG * a1);     // leaky_relu
      float lg2 = fmaxf(a2, NEG * a2);
      float ex1 = (i1 < end) ? __expf(lg1) : 0.f;
      float ex2 = (i2 < end) ? __expf(lg2) : 0.f;
      den += ex1 + ex2;
      acc[0] = fmaf(ex1, bflo(hv1.x), acc[0]); acc[0] = fmaf(ex2, bflo(hv2.x), acc[0]);
      acc[1] = fmaf(ex1, bfhi(hv1.x), acc[1]); acc[1] = fmaf(ex2, bfhi(hv2.x), acc[1]);
      acc[2] = fmaf(ex1, bflo(hv1.y), acc[2]); acc[2] = fmaf(ex2, bflo(hv2.y), acc[2]);
      acc[3] = fmaf(ex1, bfhi(hv1.y), acc[3]); acc[3] = fmaf(ex2, bfhi(hv2.y), acc[3]);
      acc[4] = fmaf(ex1, bflo(hv1.z), acc[4]); acc[4] = fmaf(ex2, bflo(hv2.z), acc[4]);
      acc[5] = fmaf(ex1, bfhi(hv1.z), acc[5]); acc[5] = fmaf(ex2, bfhi(hv2.z), acc[5]);
      acc[6] = fmaf(ex1, bflo(hv1.w), acc[6]); acc[6] = fmaf(ex2, bflo(hv2.w), acc[6]);
      acc[7] = fmaf(ex1, bfhi(hv1.w), acc[7]); acc[7] = fmaf(ex2, bfhi(hv2.w), acc[7]);
    }
#pragma unroll
    for (int off = 8; off <= 32; off <<= 1) {
      den += __shfl_xor(den, off);
#pragma unroll
      for (int c = 0; c < 8; ++c) acc[c] += __shfl_xor(acc[c], off);
    }
    float inv = 1.f / den;
    if (j == 0) {
      float4 b1a = *(const float4*)(b1 + g * 8);
      float4 b1b = *(const float4*)(b1 + g * 8 + 4);
      float4 h0, h1v;
      h0.x = fmaxf(fmaf(acc[0], inv, b1a.x), 0.f);
      h0.y = fmaxf(fmaf(acc[1], inv, b1a.y), 0.f);
      h0.z = fmaxf(fmaf(acc[2], inv, b1a.z), 0.f);
      h0.w = fmaxf(fmaf(acc[3], inv, b1a.w), 0.f);
      h1v.x = fmaxf(fmaf(acc[4], inv, b1b.x), 0.f);
      h1v.y = fmaxf(fmaf(acc[5], inv, b1b.y), 0.f);
      h1v.z = fmaxf(fmaf(acc[6], inv, b1b.z), 0.f);
      h1v.w = fmaxf(fmaf(acc[7], inv, b1b.w), 0.f);
      *(float4*)&hs[wave][g * 8]     = h0;
      *(float4*)&hs[wave][g * 8 + 4] = h1v;
    }
    // fused gemm2 (same-wave LDS, no block barrier)
    int c = lane;
    float gacc = 0.f;
    if (c < C2N) {
#pragma unroll
      for (int k = 0; k < 64; ++k) gacc = fmaf(hs[wave][k], w2s[k * C2N + c], gacc);
    }
    float asv = (c < C2N) ? gacc * att_src2[c] : 0.f;
    float adv = (c < C2N) ? gacc * att_dst2[c] : 0.f;
#pragma unroll
    for (int off = 32; off >= 1; off >>= 1) {
      asv += __shfl_xor(asv, off);
      adv += __shfl_xor(adv, off);
    }
    if (lane == 0) { asrc2[d] = asv; adst2[d] = adv; }
    if (c < C2N) gs[wave][c] = gacc;
    if (lane < 20) gb[(size_t)d * 20 + lane] = pack2bf(gs[wave][2 * lane], gs[wave][2 * lane + 1]);
  }
}

// ---------------- layer-2 edge kernel (8 edges/iter, uint4 gathers) + log_softmax ----------------
// g<=4 owns channels 8g..8g+7; g=5..7 gather in-row clamped (dwords 16..19) and are
// discarded by the j-reduction + act mask.

__global__ __launch_bounds__(256) void l2_edge_kernel(const int* __restrict__ row_ptr,
    const int* __restrict__ col, const unsigned int* __restrict__ gb,
    const float* __restrict__ asrc2, const float* __restrict__ adst2,
    const float* __restrict__ b2, float* __restrict__ out) {
  int t = threadIdx.x;
  int d = (blockIdx.x * 256 + t) >> 6;
  if (d >= NN) return;
  int lane = t & 63;
  int g = lane & 7, j = lane >> 3;
  int gq = (g < 5) ? g : 4;
  bool act = g < 5;
  int start = row_ptr[d], end = row_ptr[d + 1];
  float adst_d = adst2[d];
  float acc[8] = {0.f,0.f,0.f,0.f,0.f,0.f,0.f,0.f};
  float den = 0.f;
  for (int e = start; e < end; e += 16) {
    int i1 = e + j, i2 = e + 8 + j;
    int k1 = i1 < end ? i1 : end - 1;
    int k2 = i2 < end ? i2 : end - 1;
    int s1 = col[k1], s2 = col[k2];
    float av1 = asrc2[s1], av2 = asrc2[s2];
    uint4 g1 = *(const uint4*)(gb + (size_t)s1 * 20 + gq * 4);
    uint4 g2 = *(const uint4*)(gb + (size_t)s2 * 20 + gq * 4);
    float a1 = av1 + adst_d, a2 = av2 + adst_d;
    float lg1 = fmaxf(a1, NEG * a1);
    float lg2 = fmaxf(a2, NEG * a2);
    float ex1 = (i1 < end) ? __expf(lg1) : 0.f;
    float ex2 = (i2 < end) ? __expf(lg2) : 0.f;
    den += ex1 + ex2;
    acc[0] = fmaf(ex1, bflo(g1.x), acc[0]); acc[0] = fmaf(ex2, bflo(g2.x), acc[0]);
    acc[1] = fmaf(ex1, bfhi(g1.x), acc[1]); acc[1] = fmaf(ex2, bfhi(g2.x), acc[1]);
    acc[2] = fmaf(ex1, bflo(g1.y), acc[2]); acc[2] = fmaf(ex2, bflo(g2.y), acc[2]);
    acc[3] = fmaf(ex1, bfhi(g1.y), acc[3]); acc[3] = fmaf(ex2, bfhi(g2.y), acc[3]);
    acc[4] = fmaf(ex1, bflo(g1.z), acc[4]); acc[4] = fmaf(ex2, bflo(g2.z), acc[4]);
    acc[5] = fmaf(ex1, bfhi(g1.z), acc[5]); acc[5] = fmaf(ex2, bfhi(g2.z), acc[5]);
    acc[6] = fmaf(ex1, bflo(g1.w), acc[6]); acc[6] = fmaf(ex2, bflo(g2.w), acc[6]);
    acc[7] = fmaf(ex1, bfhi(g1.w), acc[7]); acc[7] = fmaf(ex2, bfhi(g2.w), acc[7]);
  }
#pragma unroll
  for (int off = 8; off <= 32; off <<= 1) {
    den += __shfl_xor(den, off);
#pragma unroll
    for (int c = 0; c < 8; ++c) acc[c] += __shfl_xor(acc[c], off);
  }
  float inv = 1.f / den;
  float4 b2a = *(const float4*)(b2 + gq * 8);
  float4 b2b = *(const float4*)(b2 + gq * 8 + 4);
  float o[8];
  o[0] = fmaf(acc[0], inv, b2a.x); o[1] = fmaf(acc[1], inv, b2a.y);
  o[2] = fmaf(acc[2], inv, b2a.z); o[3] = fmaf(acc[3], inv, b2a.w);
  o[4] = fmaf(acc[4], inv, b2b.x); o[5] = fmaf(acc[5], inv, b2b.y);
  o[6] = fmaf(acc[6], inv, b2b.z); o[7] = fmaf(acc[7], inv, b2b.w);
  float m = -INFINITY;
  if (act) {
#pragma unroll
    for (int i = 0; i < 8; ++i) m = fmaxf(m, o[i]);
  }
#pragma unroll
  for (int off = 1; off <= 4; off <<= 1) m = fmaxf(m, __shfl_xor(m, off));
  float es = 0.f;
  if (act) {
#pragma unroll
    for (int i = 0; i < 8; ++i) es += __expf(o[i] - m);
  }
#pragma unroll
  for (int off = 1; off <= 4; off <<= 1) es += __shfl_xor(es, off);
  float mls = m + logf(es);
  if (act && j == 0) {
    float4 r0 = make_float4(o[0] - mls, o[1] - mls, o[2] - mls, o[3] - mls);
    float4 r1 = make_float4(o[4] - mls, o[5] - mls, o[6] - mls, o[7] - mls);
    *(float4*)(out + (size_t)d * C2N + g * 8)     = r0;
    *(float4*)(out + (size_t)d * C2N + g * 8 + 4) = r1;
  }
}

// ---------------- launch ----------------

extern "C" void kernel_launch(void* const* d_in, const int* in_sizes, int n_in,
                              void* d_out, int out_size, void* d_ws, size_t ws_size,
                              hipStream_t stream) {
  const float* x        = (const float*)d_in[0];
  const int*   ei       = (const int*)d_in[1];
  const float* W1       = (const float*)d_in[2];
  const float* att_src1 = (const float*)d_in[3];
  const float* att_dst1 = (const float*)d_in[4];
  const float* b1       = (const float*)d_in[5];
  const float* W2       = (const float*)d_in[6];
  const float* att_src2 = (const float*)d_in[7];
  const float* att_dst2 = (const float*)d_in[8];
  const float* b2       = (const float*)d_in[9];
  float* out = (float*)d_out;

  char* ws = (char*)d_ws;
  size_t off = 0;
  auto alloc = [&](size_t n_elem) {
    void* p = ws + off;
    off = (off + n_elem * 4 + 255) & ~(size_t)255;
    return p;
  };
  unsigned int* h1b = (unsigned int*)alloc((size_t)NN * 32);      // bf16 packed [N][32]
  unsigned int* gb  = (unsigned int*)alloc((size_t)NN * 20 + 16); // bf16 packed [N][20] + slack
  unsigned int* bucket_glob = (unsigned int*)alloc((size_t)NB * CAPG);
  float* asrc1 = (float*)alloc((size_t)NN * 8);
  float* adst1 = (float*)alloc((size_t)NN * 8);
  float* asrc2 = (float*)alloc(NN);
  float* adst2 = (float*)alloc(NN);
  int* row_ptr = (int*)alloc(NN + 1);
  int* colv    = (int*)alloc(EE + NN);
  int* bucket_cnt  = (int*)alloc(NB);
  int* bucket_base = (int*)alloc(NB);
  short* w1t   = (short*)alloc(64 * 512 / 2);

  hipMemsetAsync(bucket_cnt, 0, NB * 4, stream);
  passA_kernel<<<PA_BLOCKS + W1T_BLOCKS, 256, 0, stream>>>(ei, bucket_cnt, bucket_glob, W1, w1t);
  scan_buckets<<<1, 512, 0, stream>>>(bucket_cnt, bucket_base, row_ptr + NN);
  passB_kernel<<<NB, 256, 0, stream>>>(bucket_glob, bucket_cnt, bucket_base, row_ptr, colv);

  gemm1_kernel<<<(NN + 63) / 64, 256, 0, stream>>>(x, w1t, (unsigned short*)h1b,
                                                   att_src1, att_dst1, asrc1, adst1);
  l1_edge_kernel<<<(NN + 15) / 16, 256, 0, stream>>>(row_ptr, colv, h1b, asrc1, adst1,
                                                     b1, W2, att_src2, att_dst2,
                                                     gb, asrc2, adst2);
  l2_edge_kernel<<<(NN * 64 + 255) / 256, 256, 0, stream>>>(row_ptr, colv, gb, asrc2, adst2, b2, out);
}